// Round 6
// baseline (608.973 us; speedup 1.0000x reference)
//
#include <hip/hip_runtime.h>
#include <math.h>

// Problem constants (match reference)
#define S     512
#define Bsz   8
#define NCELL (S*S)              // 262144 = 2^18
#define NTOT  (Bsz*NCELL)        // 2097152
#define NFACE ((S-1)*S)          // 261632
#define CG_ITERS 20
#define NITB  1024               // loop-kernel grid: 1024 blocks, 4 rows/block

__device__ __constant__ float kINVH  = 511.0f;     // 1/h
__device__ __constant__ float kINV2H = 255.5f;
__device__ __constant__ float kH2    = (float)((1.0/511.0)*(1.0/511.0));

// ---------------- geometry (replicates numpy grid_helpers bit-exactly in double) ----
__device__ __forceinline__ void geom(int i, int j, float& rhob, float& bnx, float& bny) {
    double gx = (i == S-1) ? 1.0 : (double)i * (1.0/511.0);
    double gy = (j == S-1) ? 1.0 : (double)j * (1.0/511.0);
    double v0 = gx, v1 = 1.0 - gx, v2 = gy, v3 = 1.0 - gy;
    double m = v0; int am = 0;
    if (v1 < m) { m = v1; am = 1; }   // strict '<' == np.argmin first-min-wins
    if (v2 < m) { m = v2; am = 2; }
    if (v3 < m) { m = v3; am = 3; }
    float d = (float)m;
    rhob = expf(-(d*d) / 0.0225f);
    bnx = (am == 0) ? -1.f : (am == 1) ? 1.f : 0.f;
    bny = (am == 2) ? -1.f : (am == 3) ? 1.f : 0.f;
}

// ================= K1: per-cell fields: lap, rho_int, sx, sy =======================
__global__ void k_cellfields(const float* __restrict__ coeff, const float* __restrict__ u,
                             const float* __restrict__ beta,
                             float* __restrict__ lap, float* __restrict__ rho,
                             float* __restrict__ sx, float* __restrict__ sy) {
    int idx = blockIdx.x * 256 + threadIdx.x;
    int rem = idx & (NCELL - 1);
    int i = rem >> 9, j = rem & (S - 1);
    const float* c  = coeff + (idx - rem);
    const float* uu = u     + (idx - rem);
    float cc = c[rem];

    float lapv = 0.f;
    if (i > 0 && i < S-1 && j > 0 && j < S-1) {
        float uc = uu[rem];
        float un = uu[rem + S], us = uu[rem - S];
        float ue = uu[rem + 1], uw = uu[rem - 1];
        lapv = ((un - uc)*kINVH - (uc - us)*kINVH)*kINVH
             + ((ue - uc)*kINVH - (uc - uw)*kINVH)*kINVH;
    }
    lap[idx] = lapv;

    float glx, gly;
    {
        float lc = logf(fmaxf(cc, 1e-6f));
        if (i == 0)        { glx = (logf(fmaxf(c[rem+S],1e-6f)) - lc) * kINVH; }
        else if (i == S-1) { glx = (lc - logf(fmaxf(c[rem-S],1e-6f))) * kINVH; }
        else { glx = (logf(fmaxf(c[rem+S],1e-6f)) - logf(fmaxf(c[rem-S],1e-6f))) * kINV2H; }
        if (j == 0)        { gly = (logf(fmaxf(c[rem+1],1e-6f)) - lc) * kINVH; }
        else if (j == S-1) { gly = (lc - logf(fmaxf(c[rem-1],1e-6f))) * kINVH; }
        else { gly = (logf(fmaxf(c[rem+1],1e-6f)) - logf(fmaxf(c[rem-1],1e-6f))) * kINV2H; }
    }
    float eta  = sqrtf(glx*glx + gly*gly + 1e-6f);
    float rhov = 1.f / (1.f + expf(-10.f * (eta - 0.5f)));
    float nhx = glx / eta, nhy = gly / eta;

    float4 b4 = ((const float4*)beta)[idx];
    rho[idx] = rhov;
    sx[idx]  = b4.y * nhx - b4.z * nhy;
    sy[idx]  = b4.y * nhy + b4.z * nhx;
}

// ========== K2: fused face taus + harmonic coeffs (cx/cy stored padded) ============
__global__ void k_faces(const float* __restrict__ coeff, const float* __restrict__ u,
                        const float* __restrict__ beta,
                        const float* __restrict__ lap, const float* __restrict__ rho,
                        const float* __restrict__ sx, const float* __restrict__ sy,
                        float* __restrict__ taux, float* __restrict__ tauyP,
                        float* __restrict__ cxP, float* __restrict__ cyP) {
    int idx = blockIdx.x * 256 + threadIdx.x;
    int b = idx >> 18;
    int rem = idx & (NCELL - 1);
    int i = rem >> 9, j = rem & (S - 1);

    float c0 = coeff[idx];
    float u0 = u[idx];
    float lap0 = lap[idx], rho0 = rho[idx];
    float4 b0 = ((const float4*)beta)[idx];
    float rb0, nx0, ny0; geom(i, j, rb0, nx0, ny0);

    if (i < S-1) {
        int c1i = idx + S;
        float c1 = coeff[c1i];
        float cx = 2.f * c1 * c0 / (c1 + c0 + 1e-6f);
        cxP[b * NCELL + i * S + j] = cx;          // padded width-512
        float t = 0.f;
        if (j > 0 && j < S-1) {
            float gux = (u[c1i]   - u0)   * kINVH;
            float lgx = (lap[c1i] - lap0) * kINVH;
            float4 b1 = ((const float4*)beta)[c1i];
            float rb1, nx1, ny1; geom(i+1, j, rb1, nx1, ny1);
            float abb  = 0.5f * (b1.x + b0.x);
            float arho = 0.5f * (rho[c1i] + rho0);
            float asx  = 0.5f * (sx[c1i]  + sx[idx]);
            float arb  = 0.5f * (rb1 + rb0);
            float abx  = 0.5f * (b1.w * nx1 + b0.w * nx0);
            t = abb * kH2 * cx * lgx + arho * asx * cx * gux + arb * abx * cx * gux;
        }
        taux[b * NFACE + i * S + j] = t;
    }
    if (j < S-1) {
        int c1i = idx + 1;
        float c1 = coeff[c1i];
        float cy = 2.f * c1 * c0 / (c1 + c0 + 1e-6f);
        cyP[b * NCELL + i * S + j] = cy;          // padded width-512
        float t = 0.f;
        if (i > 0 && i < S-1) {
            float guy = (u[c1i]   - u0)   * kINVH;
            float lgy = (lap[c1i] - lap0) * kINVH;
            float4 b1 = ((const float4*)beta)[c1i];
            float rb1, nx1, ny1; geom(i, j+1, rb1, nx1, ny1);
            float abb  = 0.5f * (b1.x + b0.x);
            float arho = 0.5f * (rho[c1i] + rho0);
            float asy  = 0.5f * (sy[c1i]  + sy[idx]);
            float arb  = 0.5f * (rb1 + rb0);
            float aby  = 0.5f * (b1.w * ny1 + b0.w * ny0);
            t = abb * kH2 * cy * lgy + arho * asy * cy * guy + arb * aby * cy * guy;
        }
        tauyP[b * NCELL + i * S + j] = t;
    }
}

// ================= K3: rhs = div(tau); r=p=rhs; x=0; rr partials (256/batch) =======
__global__ void k_rhs(const float* __restrict__ taux, const float* __restrict__ tauyP,
                      float* __restrict__ r, float* __restrict__ p, float* __restrict__ x,
                      double* __restrict__ rrPart) {
    __shared__ double lds[4];
    int t = blockIdx.x * 256 + threadIdx.x;
    int b = t >> 16;
    int rem = t & 65535;
    int i = rem >> 7;
    int j0 = (rem & 127) << 2;

    float4 o = make_float4(0.f, 0.f, 0.f, 0.f);
    float* oa = (float*)&o;
    if (i > 0 && i < S-1) {
        const float* tx  = taux  + b * NFACE;
        const float* typ = tauyP + b * NCELL;
        float4 txC = ((const float4*)tx)[i * 128 + (j0 >> 2)];
        float4 txS = ((const float4*)tx)[(i-1) * 128 + (j0 >> 2)];
        float4 tyC = ((const float4*)typ)[i * 128 + (j0 >> 2)];
        float tyW = (j0 > 0) ? typ[i * S + j0 - 1] : 0.f;
        const float* txCa = (const float*)&txC;
        const float* txSa = (const float*)&txS;
        const float* tyCa = (const float*)&tyC;
        #pragma unroll
        for (int k = 0; k < 4; ++k) {
            int j = j0 + k;
            if (j > 0 && j < S-1) {
                float tyw = (k == 0) ? tyW : tyCa[k-1];
                oa[k] = (txCa[k] - txSa[k]) * kINVH + (tyCa[k] - tyw) * kINVH;
            }
        }
    }
    ((float4*)r)[t] = o;
    ((float4*)p)[t] = o;
    ((float4*)x)[t] = make_float4(0.f, 0.f, 0.f, 0.f);
    double local = (double)oa[0]*oa[0] + (double)oa[1]*oa[1]
                 + (double)oa[2]*oa[2] + (double)oa[3]*oa[3];
    for (int off = 32; off > 0; off >>= 1) local += __shfl_down(local, off, 64);
    int lane = threadIdx.x & 63, wave = threadIdx.x >> 6;
    if (lane == 0) lds[wave] = local;
    __syncthreads();
    if (threadIdx.x == 0) rrPart[blockIdx.x] = lds[0]+lds[1]+lds[2]+lds[3];
}

// ====== K_ITER0: ap0 = A(p0) (4 rows/block, swizzled); dots; rn0 ===================
__global__ __launch_bounds__(256, 3) void k_iter0(
        const float* __restrict__ cxP, const float* __restrict__ cyP,
        const float* __restrict__ pIn, float* __restrict__ apOut,
        const double* __restrict__ rrPart,
        double* __restrict__ dotsOut, double* __restrict__ rnOut) {
    __shared__ double lds[8];
    int bid = blockIdx.x;
    int ebid = ((bid & 7) << 7) | (bid >> 3);     // XCD-contiguous: XCD d <- batch d
    int b  = ebid >> 7;
    int lb = ebid & 127;
    int tPair = threadIdx.x >> 7;
    int j0 = (threadIdx.x & 127) << 2;
    int i0 = lb * 4 + tPair * 2;                  // two output rows i0, i0+1
    int base = b << 18;
    int vrow = (base + (i0 << 9) + j0) >> 2;
    int lane = threadIdx.x & 63, wave = threadIdx.x >> 6;
    float4 z4 = make_float4(0.f,0.f,0.f,0.f);

    // ---- prefetch fields ----
    float4 pL[4];
    #pragma unroll
    for (int d = 0; d < 4; ++d) {
        int ir = i0 - 1 + d;
        pL[d] = (ir >= 0 && ir < S) ? ((const float4*)pIn)[vrow + (d-1)*128] : z4;
    }
    float4 cxL[3];
    #pragma unroll
    for (int d = 0; d < 3; ++d) {
        int ir = i0 - 1 + d;
        cxL[d] = (ir >= 0 && ir < S-1) ? ((const float4*)cxP)[vrow + (d-1)*128] : z4;
    }
    float4 cyL[2];
    cyL[0] = ((const float4*)cyP)[vrow];
    cyL[1] = ((const float4*)cyP)[vrow + 128];
    float pW[2]={0,0}, pE[2]={0,0}, cyW[2]={0,0};
    #pragma unroll
    for (int rr = 0; rr < 2; ++rr) {
        int idxr = base + ((i0+rr) << 9) + j0;
        if (j0 > 0)     { pW[rr] = pIn[idxr-1]; cyW[rr] = cyP[idxr-1]; }
        if (j0 + 4 < S) { pE[rr] = pIn[idxr+4]; }
    }

    // ---- rn_0 = sum of rhs partials (256 slots) ----
    {
        double v0 = rrPart[(b << 8) + threadIdx.x];
        #pragma unroll
        for (int off = 32; off > 0; off >>= 1) v0 += __shfl_down(v0, off, 64);
        if (lane == 0) lds[wave] = v0;
    }
    __syncthreads();
    double rnCur = lds[0]+lds[1]+lds[2]+lds[3];
    __syncthreads();

    double dpap = 0.0, dapap = 0.0;
    const float* pnRow[4] = {(const float*)&pL[0], (const float*)&pL[1],
                             (const float*)&pL[2], (const float*)&pL[3]};
    #pragma unroll
    for (int rr = 0; rr < 2; ++rr) {
        int i = i0 + rr;
        const float* pC = pnRow[rr+1];
        const float* pN = pnRow[rr+2];
        const float* pS = pnRow[rr];
        const float* cxU = (const float*)&cxL[rr+1];
        const float* cxD = (const float*)&cxL[rr];
        const float* cyC = (const float*)&cyL[rr];
        float apk[4];
        #pragma unroll
        for (int k = 0; k < 4; ++k) {
            int j = j0 + k;
            bool interior = (i > 0 && i < S-1 && j > 0 && j < S-1);
            float pe = (k < 3) ? pC[k+1] : pE[rr];
            float pw = (k > 0) ? pC[k-1] : pW[rr];
            float cyWv = (k > 0) ? cyC[k-1] : cyW[rr];
            float qxp = cxU[k] * ((pN[k] - pC[k]) * kINVH);
            float qxm = cxD[k] * ((pC[k] - pS[k]) * kINVH);
            float qyp = cyC[k] * ((pe - pC[k]) * kINVH);
            float qym = cyWv   * ((pC[k] - pw) * kINVH);
            float st = -((qxp - qxm) * kINVH + (qyp - qym) * kINVH);
            apk[k] = interior ? st : pC[k];
            dpap  += (double)pC[k] * (double)apk[k];
            dapap += (double)apk[k] * (double)apk[k];
        }
        float4 ao; ao.x=apk[0]; ao.y=apk[1]; ao.z=apk[2]; ao.w=apk[3];
        ((float4*)apOut)[vrow + rr*128] = ao;
    }

    #pragma unroll
    for (int off = 32; off > 0; off >>= 1) {
        dpap  += __shfl_down(dpap,  off, 64);
        dapap += __shfl_down(dapap, off, 64);
    }
    if (lane == 0) { lds[wave] = dpap; lds[4+wave] = dapap; }
    __syncthreads();
    if (threadIdx.x == 0) {
        double s1 = lds[0]+lds[1]+lds[2]+lds[3];
        dotsOut[ebid]          = s1;
        dotsOut[NITB + ebid]   = s1;     // r0 == p0
        dotsOut[2*NITB + ebid] = lds[4]+lds[5]+lds[6]+lds[7];
        if (lb == 0) rnOut[b] = rnCur;
    }
}

// ====== K_ITER: one steady CG iteration (4 rows/block, swizzled, prefetch) =========
__global__ __launch_bounds__(256, 3) void k_iter(
        const float* __restrict__ cxP, const float* __restrict__ cyP,
        const float* __restrict__ rIn,  float* __restrict__ rOut,
        const float* __restrict__ pIn,  float* __restrict__ pOut,
        const float* __restrict__ apIn, float* __restrict__ apOut,
        float* __restrict__ x,
        const double* __restrict__ dotsIn, double* __restrict__ dotsOut,
        const double* __restrict__ rnIn,  double* __restrict__ rnOut) {
    __shared__ double lds[12];
    int bid = blockIdx.x;
    int ebid = ((bid & 7) << 7) | (bid >> 3);
    int b  = ebid >> 7;
    int lb = ebid & 127;
    int tPair = threadIdx.x >> 7;
    int j0 = (threadIdx.x & 127) << 2;
    int i0 = lb * 4 + tPair * 2;
    int base = b << 18;
    int vrow = (base + (i0 << 9) + j0) >> 2;
    int lane = threadIdx.x & 63, wave = threadIdx.x >> 6;
    float4 z4 = make_float4(0.f,0.f,0.f,0.f);

    // ---- prefetch all fields (latency hidden by the scalar-reduce barrier) ----
    float4 rL[4], pL[4], aL[4];
    #pragma unroll
    for (int d = 0; d < 4; ++d) {
        int ir = i0 - 1 + d;
        bool ok = (ir >= 0 && ir < S);
        int vv = vrow + (d-1)*128;
        rL[d] = ok ? ((const float4*)rIn)[vv]  : z4;
        pL[d] = ok ? ((const float4*)pIn)[vv]  : z4;
        aL[d] = ok ? ((const float4*)apIn)[vv] : z4;
    }
    float4 cxL[3];
    #pragma unroll
    for (int d = 0; d < 3; ++d) {
        int ir = i0 - 1 + d;
        cxL[d] = (ir >= 0 && ir < S-1) ? ((const float4*)cxP)[vrow + (d-1)*128] : z4;
    }
    float4 cyL[2];
    cyL[0] = ((const float4*)cyP)[vrow];
    cyL[1] = ((const float4*)cyP)[vrow + 128];
    float rW[2]={0,0},pW[2]={0,0},aW[2]={0,0},rE[2]={0,0},pE[2]={0,0},aE[2]={0,0},cyW[2]={0,0};
    #pragma unroll
    for (int rr = 0; rr < 2; ++rr) {
        int idxr = base + ((i0+rr) << 9) + j0;
        if (j0 > 0)     { rW[rr]=rIn[idxr-1]; pW[rr]=pIn[idxr-1]; aW[rr]=apIn[idxr-1]; cyW[rr]=cyP[idxr-1]; }
        if (j0 + 4 < S) { rE[rr]=rIn[idxr+4]; pE[rr]=pIn[idxr+4]; aE[rr]=apIn[idxr+4]; }
    }
    float4 xL[2];
    xL[0] = ((const float4*)x)[vrow];
    xL[1] = ((const float4*)x)[vrow + 128];

    // ---- scalars: fused triple reduce of previous dots (128 slots/batch) ----
    {
        double v0 = 0.0, v1 = 0.0, v2 = 0.0;
        if (threadIdx.x < 128) {
            int s = (b << 7) + threadIdx.x;
            v0 = dotsIn[s];
            v1 = dotsIn[NITB + s];
            v2 = dotsIn[2*NITB + s];
        }
        #pragma unroll
        for (int off = 32; off > 0; off >>= 1) {
            v0 += __shfl_down(v0, off, 64);
            v1 += __shfl_down(v1, off, 64);
            v2 += __shfl_down(v2, off, 64);
        }
        if (lane == 0) { lds[wave] = v0; lds[4+wave] = v1; lds[8+wave] = v2; }
    }
    __syncthreads();
    double pap  = lds[0]+lds[1]+lds[2]+lds[3];
    double rap  = lds[4]+lds[5]+lds[6]+lds[7];
    double apap = lds[8]+lds[9]+lds[10]+lds[11];
    double rnPrev = rnIn[b];
    float alphaF = (float)(rnPrev / fmax(pap, 1e-6));
    double aD = (double)alphaF;
    double rnCur = rnPrev - 2.0 * aD * rap + aD * aD * apap;
    float betaF = (float)(rnCur / fmax(rnPrev, 1e-6));
    __syncthreads();

    // ---- field math: pn at 4 loaded rows; rn at output rows; ap = A(pn) ----
    float pn[4][4];
    #pragma unroll
    for (int d = 0; d < 4; ++d) {
        const float* rD = (const float*)&rL[d];
        const float* pD = (const float*)&pL[d];
        const float* aD2 = (const float*)&aL[d];
        #pragma unroll
        for (int k = 0; k < 4; ++k) {
            float rnk = rD[k] - alphaF * aD2[k];
            pn[d][k] = rnk + betaF * pD[k];
        }
    }
    float pnW[2], pnE[2];
    #pragma unroll
    for (int rr = 0; rr < 2; ++rr) {
        pnW[rr] = (rW[rr] - alphaF * aW[rr]) + betaF * pW[rr];
        pnE[rr] = (rE[rr] - alphaF * aE[rr]) + betaF * pE[rr];
    }

    double dpap = 0.0, drap = 0.0, dapap = 0.0;
    #pragma unroll
    for (int rr = 0; rr < 2; ++rr) {
        int i = i0 + rr;
        const float* rC = (const float*)&rL[rr+1];
        const float* pC = (const float*)&pL[rr+1];
        const float* aC = (const float*)&aL[rr+1];
        const float* cxU = (const float*)&cxL[rr+1];
        const float* cxD = (const float*)&cxL[rr];
        const float* cyC = (const float*)&cyL[rr];
        float* xr = (float*)&xL[rr];
        float rnc[4], apk[4];
        #pragma unroll
        for (int k = 0; k < 4; ++k) {
            int j = j0 + k;
            bool interior = (i > 0 && i < S-1 && j > 0 && j < S-1);
            rnc[k] = rC[k] - alphaF * aC[k];
            xr[k]  = xr[k] + alphaF * pC[k];
            float pe = (k < 3) ? pn[rr+1][k+1] : pnE[rr];
            float pw = (k > 0) ? pn[rr+1][k-1] : pnW[rr];
            float cyWv = (k > 0) ? cyC[k-1] : cyW[rr];
            float qxp = cxU[k] * ((pn[rr+2][k] - pn[rr+1][k]) * kINVH);
            float qxm = cxD[k] * ((pn[rr+1][k] - pn[rr][k]) * kINVH);
            float qyp = cyC[k] * ((pe - pn[rr+1][k]) * kINVH);
            float qym = cyWv   * ((pn[rr+1][k] - pw) * kINVH);
            float st = -((qxp - qxm) * kINVH + (qyp - qym) * kINVH);
            apk[k] = interior ? st : pn[rr+1][k];
            dpap  += (double)pn[rr+1][k] * (double)apk[k];
            drap  += (double)rnc[k]      * (double)apk[k];
            dapap += (double)apk[k]      * (double)apk[k];
        }
        float4 ao; ao.x=apk[0]; ao.y=apk[1]; ao.z=apk[2]; ao.w=apk[3];
        float4 ro; ro.x=rnc[0]; ro.y=rnc[1]; ro.z=rnc[2]; ro.w=rnc[3];
        float4 po; po.x=pn[rr+1][0]; po.y=pn[rr+1][1]; po.z=pn[rr+1][2]; po.w=pn[rr+1][3];
        ((float4*)apOut)[vrow + rr*128] = ao;
        ((float4*)rOut)[vrow + rr*128]  = ro;
        ((float4*)pOut)[vrow + rr*128]  = po;
        ((float4*)x)[vrow + rr*128]     = xL[rr];
    }

    // ---- fused triple block-sum of new dots ----
    #pragma unroll
    for (int off = 32; off > 0; off >>= 1) {
        dpap  += __shfl_down(dpap,  off, 64);
        drap  += __shfl_down(drap,  off, 64);
        dapap += __shfl_down(dapap, off, 64);
    }
    __syncthreads();
    if (lane == 0) { lds[wave] = dpap; lds[4+wave] = drap; lds[8+wave] = dapap; }
    __syncthreads();
    if (threadIdx.x == 0) {
        dotsOut[ebid]          = lds[0]+lds[1]+lds[2]+lds[3];
        dotsOut[NITB + ebid]   = lds[4]+lds[5]+lds[6]+lds[7];
        dotsOut[2*NITB + ebid] = lds[8]+lds[9]+lds[10]+lds[11];
        if (lb == 0) rnOut[b] = rnCur;
    }
}

// ====== KF: final alpha; out = zb(u + x + alpha*p_19) ==============================
__global__ void k_fin(const float* __restrict__ u, const float* __restrict__ p,
                      float* __restrict__ out,
                      const double* __restrict__ dotsIn, const double* __restrict__ rnIn) {
    __shared__ double lds[4];
    int t = blockIdx.x * 256 + threadIdx.x;
    int b = t >> 16;
    int lane = threadIdx.x & 63, wave = threadIdx.x >> 6;
    {
        double v0 = (threadIdx.x < 128) ? dotsIn[(b << 7) + threadIdx.x] : 0.0;
        #pragma unroll
        for (int off = 32; off > 0; off >>= 1) v0 += __shfl_down(v0, off, 64);
        if (lane == 0) lds[wave] = v0;
    }
    __syncthreads();
    double pap = lds[0]+lds[1]+lds[2]+lds[3];
    float alpha = (float)(rnIn[b] / fmax(pap, 1e-6));
    int rem = t & 65535;
    int i = rem >> 7;
    int j0 = (rem & 127) << 2;
    float4 o = make_float4(0.f,0.f,0.f,0.f);
    if (i > 0 && i < S-1) {
        float4 u4 = ((const float4*)u)[t];
        float4 x4 = ((const float4*)out)[t];
        float4 p4 = ((const float4*)p)[t];
        const float* ua=(const float*)&u4; const float* xa=(const float*)&x4;
        const float* pa=(const float*)&p4; float* oa=(float*)&o;
        #pragma unroll
        for (int k = 0; k < 4; ++k) {
            int j = j0 + k;
            if (j > 0 && j < S-1) oa[k] = ua[k] + xa[k] + alpha * pa[k];
        }
    }
    ((float4*)out)[t] = o;
}

extern "C" void kernel_launch(void* const* d_in, const int* in_sizes, int n_in,
                              void* d_out, int out_size, void* d_ws, size_t ws_size,
                              hipStream_t stream) {
    const float* coeff = (const float*)d_in[0];
    const float* u     = (const float*)d_in[1];
    const float* beta  = (const float*)d_in[2];
    float* x = (float*)d_out;

    // ws: 8 cell-sized float arrays (64 MB) + double partials.
    float* fb  = (float*)d_ws;
    float* rA  = fb;
    float* rB  = rA  + NTOT;
    float* pA  = rB  + NTOT;
    float* pB  = pA  + NTOT;
    float* apA = pB  + NTOT;     // = tauyP during setup
    float* apB = apA + NTOT;     // = taux  during setup
    float* cxP = apB + NTOT;
    float* cyP = cxP + NTOT;
    double* rrPart = (double*)(cyP + NTOT);   // 2048
    double* setA   = rrPart + 2048;           // 3*NITB
    double* setB   = setA + 3*NITB;
    double* rnA    = setB + 3*NITB;           // Bsz
    double* rnB    = rnA + Bsz;

    dim3 blk(256);

    k_cellfields<<<8192, blk, 0, stream>>>(coeff, u, beta, rB, pB, rA, pA);
    k_faces<<<8192, blk, 0, stream>>>(coeff, u, beta, rB, pB, rA, pA,
                                      apB /*taux*/, apA /*tauyP*/, cxP, cyP);
    k_rhs<<<2048, blk, 0, stream>>>(apB, apA, rA, pA, x, rrPart);
    k_iter0<<<NITB, blk, 0, stream>>>(cxP, cyP, pA, apA, rrPart, setA, rnA);

    const float *ri=rA, *pi=pA, *ai=apA;
    float *ro=rB, *po=pB, *ao=apB;
    const double *dIn=setA, *rnIn=rnA;
    double *dOut=setB, *rnOut=rnB;
    for (int it = 1; it < CG_ITERS; ++it) {
        k_iter<<<NITB, blk, 0, stream>>>(cxP, cyP, ri, ro, pi, po, ai, ao,
                                         x, dIn, dOut, rnIn, rnOut);
        { const float* s=ri; ri=ro; ro=(float*)s; }
        { const float* s=pi; pi=po; po=(float*)s; }
        { const float* s=ai; ai=ao; ao=(float*)s; }
        { const double* s=dIn; dIn=dOut; dOut=(double*)s; }
        { const double* s=rnIn; rnIn=rnOut; rnOut=(double*)s; }
    }

    k_fin<<<2048, blk, 0, stream>>>(u, pi, x, dIn, rnIn);
}

// Round 7
// 546.045 us; speedup vs baseline: 1.1152x; 1.1152x over previous
//
#include <hip/hip_runtime.h>
#include <math.h>

// Problem constants (match reference)
#define S     512
#define Bsz   8
#define NCELL (S*S)              // 262144 = 2^18
#define NTOT  (Bsz*NCELL)        // 2097152
#define NFACE ((S-1)*S)          // 261632
#define CG_ITERS 20
#define NBLK  2048               // loop-kernel grid (256 blocks/batch, 2 rows/block)

__device__ __constant__ float kINVH  = 511.0f;     // 1/h
__device__ __constant__ float kINV2H = 255.5f;
__device__ __constant__ float kH2    = (float)((1.0/511.0)*(1.0/511.0));

// ---------------- geometry (replicates numpy grid_helpers bit-exactly in double) ----
__device__ __forceinline__ void geom(int i, int j, float& rhob, float& bnx, float& bny) {
    double gx = (i == S-1) ? 1.0 : (double)i * (1.0/511.0);
    double gy = (j == S-1) ? 1.0 : (double)j * (1.0/511.0);
    double v0 = gx, v1 = 1.0 - gx, v2 = gy, v3 = 1.0 - gy;
    double m = v0; int am = 0;
    if (v1 < m) { m = v1; am = 1; }   // strict '<' == np.argmin first-min-wins
    if (v2 < m) { m = v2; am = 2; }
    if (v3 < m) { m = v3; am = 3; }
    float d = (float)m;
    rhob = expf(-(d*d) / 0.0225f);
    bnx = (am == 0) ? -1.f : (am == 1) ? 1.f : 0.f;
    bny = (am == 2) ? -1.f : (am == 3) ? 1.f : 0.f;
}

// ---- per-cell fields (lap, rho, sx, sy) at (i,j); pointers pre-offset to batch ----
// Expressions identical to R5's k_cellfields -> bit-identical values.
__device__ __forceinline__ void cellfield(const float* __restrict__ c,
                                          const float* __restrict__ uu,
                                          const float* __restrict__ bb,   // batch beta, float base
                                          int i, int j,
                                          float& lapv, float& rhov,
                                          float& sxv, float& syv) {
    int rem = i * S + j;
    float cc = c[rem];
    lapv = 0.f;
    if (i > 0 && i < S-1 && j > 0 && j < S-1) {
        float uc = uu[rem];
        float un = uu[rem + S], us = uu[rem - S];
        float ue = uu[rem + 1], uw = uu[rem - 1];
        lapv = ((un - uc)*kINVH - (uc - us)*kINVH)*kINVH
             + ((ue - uc)*kINVH - (uc - uw)*kINVH)*kINVH;
    }
    float glx, gly;
    float lc = logf(fmaxf(cc, 1e-6f));
    if (i == 0)        { glx = (logf(fmaxf(c[rem+S],1e-6f)) - lc) * kINVH; }
    else if (i == S-1) { glx = (lc - logf(fmaxf(c[rem-S],1e-6f))) * kINVH; }
    else { glx = (logf(fmaxf(c[rem+S],1e-6f)) - logf(fmaxf(c[rem-S],1e-6f))) * kINV2H; }
    if (j == 0)        { gly = (logf(fmaxf(c[rem+1],1e-6f)) - lc) * kINVH; }
    else if (j == S-1) { gly = (lc - logf(fmaxf(c[rem-1],1e-6f))) * kINVH; }
    else { gly = (logf(fmaxf(c[rem+1],1e-6f)) - logf(fmaxf(c[rem-1],1e-6f))) * kINV2H; }
    float eta  = sqrtf(glx*glx + gly*gly + 1e-6f);
    rhov = 1.f / (1.f + expf(-10.f * (eta - 0.5f)));
    float nhx = glx / eta, nhy = gly / eta;
    float4 b4 = ((const float4*)bb)[rem];
    sxv = b4.y * nhx - b4.z * nhy;
    syv = b4.y * nhy + b4.z * nhx;
}

// ========== K_SETUP: fused cell fields + face taus + harmonic coeffs ===============
// One thread per cell; recomputes neighbor fields (N, E) instead of staging them.
__global__ void k_setup(const float* __restrict__ coeff, const float* __restrict__ u,
                        const float* __restrict__ beta,
                        float* __restrict__ taux, float* __restrict__ tauyP,
                        float* __restrict__ cxP, float* __restrict__ cyP) {
    int idx = blockIdx.x * 256 + threadIdx.x;
    int b = idx >> 18;
    int rem = idx & (NCELL - 1);
    int i = rem >> 9, j = rem & (S - 1);
    const float* cB = coeff + (b << 18);
    const float* uB = u     + (b << 18);
    const float* bB = beta  + ((size_t)b << 20);   // b*NCELL*4 floats

    float lap0, rho0, sx0, sy0;
    cellfield(cB, uB, bB, i, j, lap0, rho0, sx0, sy0);
    float c0 = cB[rem], u0 = uB[rem];
    float4 b0 = ((const float4*)bB)[rem];
    float rb0, nx0, ny0; geom(i, j, rb0, nx0, ny0);

    if (i < S-1) {                                  // x-face (i,j): cells (i,j),(i+1,j)
        float lap1, rho1, sx1, sy1;
        cellfield(cB, uB, bB, i+1, j, lap1, rho1, sx1, sy1);
        float c1 = cB[rem + S];
        float cx = 2.f * c1 * c0 / (c1 + c0 + 1e-6f);
        cxP[(b << 18) + rem] = cx;                  // padded width-512
        float t = 0.f;
        if (j > 0 && j < S-1) {
            float gux = (uB[rem + S] - u0) * kINVH;
            float lgx = (lap1 - lap0) * kINVH;
            float4 b1 = ((const float4*)bB)[rem + S];
            float rb1, nx1, ny1; geom(i+1, j, rb1, nx1, ny1);
            float abb  = 0.5f * (b1.x + b0.x);
            float arho = 0.5f * (rho1 + rho0);
            float asx  = 0.5f * (sx1 + sx0);
            float arb  = 0.5f * (rb1 + rb0);
            float abx  = 0.5f * (b1.w * nx1 + b0.w * nx0);
            t = abb * kH2 * cx * lgx + arho * asx * cx * gux + arb * abx * cx * gux;
        }
        taux[b * NFACE + rem] = t;
    }
    if (j < S-1) {                                  // y-face (i,j): cells (i,j),(i,j+1)
        float lap1, rho1, sx1, sy1;
        cellfield(cB, uB, bB, i, j+1, lap1, rho1, sx1, sy1);
        float c1 = cB[rem + 1];
        float cy = 2.f * c1 * c0 / (c1 + c0 + 1e-6f);
        cyP[(b << 18) + rem] = cy;                  // padded width-512
        float t = 0.f;
        if (i > 0 && i < S-1) {
            float guy = (uB[rem + 1] - u0) * kINVH;
            float lgy = (lap1 - lap0) * kINVH;
            float4 b1 = ((const float4*)bB)[rem + 1];
            float rb1, nx1, ny1; geom(i, j+1, rb1, nx1, ny1);
            float abb  = 0.5f * (b1.x + b0.x);
            float arho = 0.5f * (rho1 + rho0);
            float asy  = 0.5f * (sy1 + sy0);
            float arb  = 0.5f * (rb1 + rb0);
            float aby  = 0.5f * (b1.w * ny1 + b0.w * ny0);
            t = abb * kH2 * cy * lgy + arho * asy * cy * guy + arb * aby * cy * guy;
        }
        tauyP[(b << 18) + rem] = t;
    }
}

// ================= K3: rhs = div(tau); r=p=rhs; x=0; rr partials (256/batch) =======
__global__ void k_rhs(const float* __restrict__ taux, const float* __restrict__ tauyP,
                      float* __restrict__ r, float* __restrict__ p, float* __restrict__ x,
                      double* __restrict__ rrPart) {
    __shared__ double lds[4];
    int t = blockIdx.x * 256 + threadIdx.x;
    int b = t >> 16;
    int rem = t & 65535;
    int i = rem >> 7;
    int j0 = (rem & 127) << 2;

    float4 o = make_float4(0.f, 0.f, 0.f, 0.f);
    float* oa = (float*)&o;
    if (i > 0 && i < S-1) {
        const float* tx  = taux  + b * NFACE;
        const float* typ = tauyP + b * NCELL;
        float4 txC = ((const float4*)tx)[i * 128 + (j0 >> 2)];
        float4 txS = ((const float4*)tx)[(i-1) * 128 + (j0 >> 2)];
        float4 tyC = ((const float4*)typ)[i * 128 + (j0 >> 2)];
        float tyW = (j0 > 0) ? typ[i * S + j0 - 1] : 0.f;
        const float* txCa = (const float*)&txC;
        const float* txSa = (const float*)&txS;
        const float* tyCa = (const float*)&tyC;
        #pragma unroll
        for (int k = 0; k < 4; ++k) {
            int j = j0 + k;
            if (j > 0 && j < S-1) {
                float tyw = (k == 0) ? tyW : tyCa[k-1];
                oa[k] = (txCa[k] - txSa[k]) * kINVH + (tyCa[k] - tyw) * kINVH;
            }
        }
    }
    ((float4*)r)[t] = o;
    ((float4*)p)[t] = o;
    ((float4*)x)[t] = make_float4(0.f, 0.f, 0.f, 0.f);
    double local = (double)oa[0]*oa[0] + (double)oa[1]*oa[1]
                 + (double)oa[2]*oa[2] + (double)oa[3]*oa[3];
    for (int off = 32; off > 0; off >>= 1) local += __shfl_down(local, off, 64);
    int lane = threadIdx.x & 63, wave = threadIdx.x >> 6;
    if (lane == 0) lds[wave] = local;
    __syncthreads();
    if (threadIdx.x == 0) rrPart[blockIdx.x] = lds[0]+lds[1]+lds[2]+lds[3];
}

// ====== K_ITER0: ap0 = A(p0); dots; rn0 from rrPart (R5-proven version) ============
__global__ __launch_bounds__(256, 4) void k_iter0(
        const float* __restrict__ cxP, const float* __restrict__ cyP,
        const float* __restrict__ pIn, float* __restrict__ apOut,
        const double* __restrict__ rrPart,
        double* __restrict__ dotsOut, double* __restrict__ rnOut) {
    __shared__ double lds[12];
    int t = blockIdx.x * 256 + threadIdx.x;
    int b = t >> 16;
    int rem = t & 65535;
    int i = rem >> 7;
    int j0 = (rem & 127) << 2;
    int idx = (b << 18) + (i << 9) + j0;
    int v = idx >> 2;
    int lane = threadIdx.x & 63, wave = threadIdx.x >> 6;

    // rn_0 = sum of rhs partials
    {
        double v0 = rrPart[(b << 8) + threadIdx.x];
        #pragma unroll
        for (int off = 32; off > 0; off >>= 1) v0 += __shfl_down(v0, off, 64);
        if (lane == 0) lds[wave] = v0;
    }
    __syncthreads();
    double rnCur = lds[0]+lds[1]+lds[2]+lds[3];
    __syncthreads();

    double dpap = 0.0, dapap = 0.0;
    if (i > 0 && i < S-1) {
        const float4* p4p = (const float4*)pIn;
        float4 pC4 = p4p[v], pN4 = p4p[v+128], pS4 = p4p[v-128];
        float4 cx4 = ((const float4*)cxP)[v];
        float4 cs4 = ((const float4*)cxP)[v-128];
        float4 cy4 = ((const float4*)cyP)[v];
        const float* pCa=(const float*)&pC4; const float* pNa=(const float*)&pN4;
        const float* pSa=(const float*)&pS4;
        const float* cxa=(const float*)&cx4; const float* csa=(const float*)&cs4;
        const float* cya=(const float*)&cy4;
        float cyWs = (j0 > 0)     ? cyP[idx-1] : 0.f;
        float pW   = (j0 > 0)     ? pIn[idx-1] : 0.f;
        float pE   = (j0 + 4 < S) ? pIn[idx+4] : 0.f;

        float apk[4];
        #pragma unroll
        for (int k = 0; k < 4; ++k) {
            int j = j0 + k;
            if (j > 0 && j < S-1) {
                float pe = (k < 3) ? pCa[k+1] : pE;
                float pw = (k > 0) ? pCa[k-1] : pW;
                float cyWk = (k > 0) ? cya[k-1] : cyWs;
                float qxp = cxa[k] * ((pNa[k] - pCa[k]) * kINVH);
                float qxm = csa[k] * ((pCa[k] - pSa[k]) * kINVH);
                float qyp = cya[k] * ((pe - pCa[k]) * kINVH);
                float qym = cyWk   * ((pCa[k] - pw) * kINVH);
                apk[k] = -((qxp - qxm) * kINVH + (qyp - qym) * kINVH);
            } else {
                apk[k] = pCa[k];               // Dirichlet (value is 0)
            }
            dpap  += (double)pCa[k] * (double)apk[k];
            dapap += (double)apk[k] * (double)apk[k];
        }
        float4 ao; ao.x=apk[0]; ao.y=apk[1]; ao.z=apk[2]; ao.w=apk[3];
        ((float4*)apOut)[v] = ao;
    } else {
        ((float4*)apOut)[v] = make_float4(0.f,0.f,0.f,0.f);
    }

    #pragma unroll
    for (int off = 32; off > 0; off >>= 1) {
        dpap  += __shfl_down(dpap,  off, 64);
        dapap += __shfl_down(dapap, off, 64);
    }
    __syncthreads();
    if (lane == 0) { lds[wave] = dpap; lds[4+wave] = dapap; }
    __syncthreads();
    if (threadIdx.x == 0) {
        double s1 = lds[0]+lds[1]+lds[2]+lds[3];
        dotsOut[blockIdx.x]          = s1;
        dotsOut[NBLK + blockIdx.x]   = s1;     // r0 == p0 -> <r,ap> == <p,ap>
        dotsOut[2*NBLK + blockIdx.x] = lds[4]+lds[5]+lds[6]+lds[7];
        if ((blockIdx.x & 255) == 0) rnOut[b] = rnCur;
    }
}

// ====== K_ITER: one full steady CG iteration (R5-proven version) ===================
__global__ __launch_bounds__(256, 4) void k_iter(
        const float* __restrict__ cxP, const float* __restrict__ cyP,
        const float* __restrict__ rIn,  float* __restrict__ rOut,
        const float* __restrict__ pIn,  float* __restrict__ pOut,
        const float* __restrict__ apIn, float* __restrict__ apOut,
        float* __restrict__ x,
        const double* __restrict__ dotsIn, double* __restrict__ dotsOut,
        const double* __restrict__ rnIn,  double* __restrict__ rnOut) {
    __shared__ double lds[12];
    int t = blockIdx.x * 256 + threadIdx.x;
    int b = t >> 16;
    int rem = t & 65535;
    int i = rem >> 7;
    int j0 = (rem & 127) << 2;
    int idx = (b << 18) + (i << 9) + j0;
    int v = idx >> 2;
    int lane = threadIdx.x & 63, wave = threadIdx.x >> 6;

    // ---- scalars: fused triple reduce of previous dots ----
    {
        int s = (b << 8) + threadIdx.x;
        double v0 = dotsIn[s];
        double v1 = dotsIn[NBLK + s];
        double v2 = dotsIn[2*NBLK + s];
        #pragma unroll
        for (int off = 32; off > 0; off >>= 1) {
            v0 += __shfl_down(v0, off, 64);
            v1 += __shfl_down(v1, off, 64);
            v2 += __shfl_down(v2, off, 64);
        }
        if (lane == 0) { lds[wave] = v0; lds[4+wave] = v1; lds[8+wave] = v2; }
    }
    __syncthreads();
    double pap  = lds[0]+lds[1]+lds[2]+lds[3];
    double rap  = lds[4]+lds[5]+lds[6]+lds[7];
    double apap = lds[8]+lds[9]+lds[10]+lds[11];
    double rnPrev = rnIn[b];
    float alphaF = (float)(rnPrev / fmax(pap, 1e-6));
    double aD = (double)alphaF;
    double rnCur = rnPrev - 2.0 * aD * rap + aD * aD * apap;
    float betaF = (float)(rnCur / fmax(rnPrev, 1e-6));

    double dpap = 0.0, drap = 0.0, dapap = 0.0;
    if (i > 0 && i < S-1) {
        const float4* r4p = (const float4*)rIn;
        const float4* p4p = (const float4*)pIn;
        const float4* a4p = (const float4*)apIn;
        float4 rC4=r4p[v], rN4=r4p[v+128], rS4=r4p[v-128];
        float4 pC4=p4p[v], pN4=p4p[v+128], pS4=p4p[v-128];
        float4 aC4=a4p[v], aN4=a4p[v+128], aS4=a4p[v-128];
        float4 cx4 = ((const float4*)cxP)[v];
        float4 cs4 = ((const float4*)cxP)[v-128];
        float4 cy4 = ((const float4*)cyP)[v];
        const float* rCa=(const float*)&rC4; const float* rNa=(const float*)&rN4;
        const float* rSa=(const float*)&rS4;
        const float* pCa=(const float*)&pC4; const float* pNa=(const float*)&pN4;
        const float* pSa=(const float*)&pS4;
        const float* aCa=(const float*)&aC4; const float* aNa=(const float*)&aN4;
        const float* aSa=(const float*)&aS4;
        const float* cxa=(const float*)&cx4; const float* csa=(const float*)&cs4;
        const float* cya=(const float*)&cy4;
        float cyWs = (j0 > 0) ? cyP[idx-1] : 0.f;
        float rW=0.f,pW=0.f,aW=0.f,rE=0.f,pE=0.f,aE=0.f;
        if (j0 > 0)     { rW = rIn[idx-1]; pW = pIn[idx-1]; aW = apIn[idx-1]; }
        if (j0 + 4 < S) { rE = rIn[idx+4]; pE = pIn[idx+4]; aE = apIn[idx+4]; }

        // x += alpha * p_old
        float4 x4 = ((const float4*)x)[v];
        x4.x += alphaF * pCa[0]; x4.y += alphaF * pCa[1];
        x4.z += alphaF * pCa[2]; x4.w += alphaF * pCa[3];
        ((float4*)x)[v] = x4;

        float pnC[4], pnN[4], pnS[4], rnC[4];
        #pragma unroll
        for (int k = 0; k < 4; ++k) {
            rnC[k]     = rCa[k] - alphaF * aCa[k];
            pnC[k]     = rnC[k] + betaF * pCa[k];
            float rnNk = rNa[k] - alphaF * aNa[k];
            pnN[k]     = rnNk   + betaF * pNa[k];
            float rnSk = rSa[k] - alphaF * aSa[k];
            pnS[k]     = rnSk   + betaF * pSa[k];
        }
        float pnW = (rW - alphaF * aW) + betaF * pW;
        float pnE = (rE - alphaF * aE) + betaF * pE;

        float apk[4];
        #pragma unroll
        for (int k = 0; k < 4; ++k) {
            int j = j0 + k;
            if (j > 0 && j < S-1) {
                float pe = (k < 3) ? pnC[k+1] : pnE;
                float pw = (k > 0) ? pnC[k-1] : pnW;
                float cyWk = (k > 0) ? cya[k-1] : cyWs;
                float qxp = cxa[k] * ((pnN[k] - pnC[k]) * kINVH);
                float qxm = csa[k] * ((pnC[k] - pnS[k]) * kINVH);
                float qyp = cya[k] * ((pe - pnC[k]) * kINVH);
                float qym = cyWk   * ((pnC[k] - pw) * kINVH);
                apk[k] = -((qxp - qxm) * kINVH + (qyp - qym) * kINVH);
            } else {
                apk[k] = pnC[k];               // Dirichlet (value is 0)
            }
            dpap  += (double)pnC[k] * (double)apk[k];
            drap  += (double)rnC[k] * (double)apk[k];
            dapap += (double)apk[k] * (double)apk[k];
        }

        float4 ao; ao.x=apk[0]; ao.y=apk[1]; ao.z=apk[2]; ao.w=apk[3];
        float4 ro; ro.x=rnC[0]; ro.y=rnC[1]; ro.z=rnC[2]; ro.w=rnC[3];
        float4 po; po.x=pnC[0]; po.y=pnC[1]; po.z=pnC[2]; po.w=pnC[3];
        ((float4*)apOut)[v] = ao;
        ((float4*)rOut)[v] = ro;
        ((float4*)pOut)[v] = po;
    } else {
        float4 z = make_float4(0.f,0.f,0.f,0.f);
        ((float4*)apOut)[v] = z;
        ((float4*)rOut)[v] = z;
        ((float4*)pOut)[v] = z;
    }

    // ---- fused triple block-sum of new dots ----
    #pragma unroll
    for (int off = 32; off > 0; off >>= 1) {
        dpap  += __shfl_down(dpap,  off, 64);
        drap  += __shfl_down(drap,  off, 64);
        dapap += __shfl_down(dapap, off, 64);
    }
    __syncthreads();
    if (lane == 0) { lds[wave] = dpap; lds[4+wave] = drap; lds[8+wave] = dapap; }
    __syncthreads();
    if (threadIdx.x == 0) {
        dotsOut[blockIdx.x]          = lds[0]+lds[1]+lds[2]+lds[3];
        dotsOut[NBLK + blockIdx.x]   = lds[4]+lds[5]+lds[6]+lds[7];
        dotsOut[2*NBLK + blockIdx.x] = lds[8]+lds[9]+lds[10]+lds[11];
        if ((blockIdx.x & 255) == 0) rnOut[b] = rnCur;
    }
}

// ====== KF: final alpha; out = zb(u + x + alpha*p_19) ==============================
__global__ void k_fin(const float* __restrict__ u, const float* __restrict__ p,
                      float* __restrict__ out,
                      const double* __restrict__ dotsIn, const double* __restrict__ rnIn) {
    __shared__ double lds[4];
    int t = blockIdx.x * 256 + threadIdx.x;
    int b = t >> 16;
    int lane = threadIdx.x & 63, wave = threadIdx.x >> 6;
    {
        double v0 = dotsIn[(b << 8) + threadIdx.x];
        #pragma unroll
        for (int off = 32; off > 0; off >>= 1) v0 += __shfl_down(v0, off, 64);
        if (lane == 0) lds[wave] = v0;
    }
    __syncthreads();
    double pap = lds[0]+lds[1]+lds[2]+lds[3];
    float alpha = (float)(rnIn[b] / fmax(pap, 1e-6));
    int rem = t & 65535;
    int i = rem >> 7;
    int j0 = (rem & 127) << 2;
    float4 o = make_float4(0.f,0.f,0.f,0.f);
    if (i > 0 && i < S-1) {
        float4 u4 = ((const float4*)u)[t];
        float4 x4 = ((const float4*)out)[t];
        float4 p4 = ((const float4*)p)[t];
        const float* ua=(const float*)&u4; const float* xa=(const float*)&x4;
        const float* pa=(const float*)&p4; float* oa=(float*)&o;
        #pragma unroll
        for (int k = 0; k < 4; ++k) {
            int j = j0 + k;
            if (j > 0 && j < S-1) oa[k] = ua[k] + xa[k] + alpha * pa[k];
        }
    }
    ((float4*)out)[t] = o;
}

extern "C" void kernel_launch(void* const* d_in, const int* in_sizes, int n_in,
                              void* d_out, int out_size, void* d_ws, size_t ws_size,
                              hipStream_t stream) {
    const float* coeff = (const float*)d_in[0];
    const float* u     = (const float*)d_in[1];
    const float* beta  = (const float*)d_in[2];
    float* x = (float*)d_out;

    // ws: 8 cell-sized float arrays (64 MB) + double partials.
    // Overlays: taux->apB, tauyP->apA (consumed by k_rhs/k_iter0 before overwritten).
    float* fb  = (float*)d_ws;
    float* rA  = fb;
    float* rB  = rA  + NTOT;
    float* pA  = rB  + NTOT;
    float* pB  = pA  + NTOT;
    float* apA = pB  + NTOT;     // = tauyP during setup
    float* apB = apA + NTOT;     // = taux  during setup
    float* cxP = apB + NTOT;
    float* cyP = cxP + NTOT;
    double* rrPart = (double*)(cyP + NTOT);   // NBLK
    double* setA   = rrPart + NBLK;           // 3*NBLK
    double* setB   = setA + 3*NBLK;
    double* rnA    = setB + 3*NBLK;           // Bsz
    double* rnB    = rnA + Bsz;

    dim3 blk(256);

    k_setup<<<8192, blk, 0, stream>>>(coeff, u, beta,
                                      apB /*taux*/, apA /*tauyP*/, cxP, cyP);
    k_rhs<<<NBLK, blk, 0, stream>>>(apB, apA, rA, pA, x, rrPart);
    k_iter0<<<NBLK, blk, 0, stream>>>(cxP, cyP, pA, apA, rrPart, setA, rnA);

    const float *ri=rA, *pi=pA, *ai=apA;
    float *ro=rB, *po=pB, *ao=apB;
    const double *dIn=setA, *rnIn=rnA;
    double *dOut=setB, *rnOut=rnB;
    for (int it = 1; it < CG_ITERS; ++it) {
        k_iter<<<NBLK, blk, 0, stream>>>(cxP, cyP, ri, ro, pi, po, ai, ao,
                                         x, dIn, dOut, rnIn, rnOut);
        { const float* s=ri; ri=ro; ro=(float*)s; }
        { const float* s=pi; pi=po; po=(float*)s; }
        { const float* s=ai; ai=ao; ao=(float*)s; }
        { const double* s=dIn; dIn=dOut; dOut=(double*)s; }
        { const double* s=rnIn; rnIn=rnOut; rnOut=(double*)s; }
    }

    k_fin<<<NBLK, blk, 0, stream>>>(u, pi, x, dIn, rnIn);
}

// Round 8
// 526.400 us; speedup vs baseline: 1.1569x; 1.0373x over previous
//
#include <hip/hip_runtime.h>
#include <math.h>

// Problem constants (match reference)
#define S     512
#define Bsz   8
#define NCELL (S*S)              // 262144 = 2^18
#define NTOT  (Bsz*NCELL)        // 2097152
#define NFACE ((S-1)*S)          // 261632
#define CG_ITERS 20
#define NBLK  2048               // loop-kernel grid (256 blocks/batch, 2 rows/block)
#define TS    16                 // k_setup tile

__device__ __constant__ float kINVH  = 511.0f;     // 1/h
__device__ __constant__ float kINV2H = 255.5f;
__device__ __constant__ float kH2    = (float)((1.0/511.0)*(1.0/511.0));

// ---------------- geometry (replicates numpy grid_helpers bit-exactly in double) ----
__device__ __forceinline__ void geom(int i, int j, float& rhob, float& bnx, float& bny) {
    double gx = (i == S-1) ? 1.0 : (double)i * (1.0/511.0);
    double gy = (j == S-1) ? 1.0 : (double)j * (1.0/511.0);
    double v0 = gx, v1 = 1.0 - gx, v2 = gy, v3 = 1.0 - gy;
    double m = v0; int am = 0;
    if (v1 < m) { m = v1; am = 1; }   // strict '<' == np.argmin first-min-wins
    if (v2 < m) { m = v2; am = 2; }
    if (v3 < m) { m = v3; am = 3; }
    float d = (float)m;
    rhob = expf(-(d*d) / 0.0225f);
    bnx = (am == 0) ? -1.f : (am == 1) ? 1.f : 0.f;
    bny = (am == 2) ? -1.f : (am == 3) ? 1.f : 0.f;
}

// ---- per-cell fields; expressions identical to R7 -> bit-identical values ---------
// f[0]=lap f[1]=rho f[2]=sx f[3]=sy f[4]=coeff f[5]=u f[6]=beta.x f[7]=beta.w
__device__ __forceinline__ void cellfield8(const float* __restrict__ c,
                                           const float* __restrict__ uu,
                                           const float* __restrict__ bb,
                                           int i, int j, float* f) {
    int rem = i * S + j;
    float cc = c[rem];
    float uc = uu[rem];
    float lapv = 0.f;
    if (i > 0 && i < S-1 && j > 0 && j < S-1) {
        float un = uu[rem + S], us = uu[rem - S];
        float ue = uu[rem + 1], uw = uu[rem - 1];
        lapv = ((un - uc)*kINVH - (uc - us)*kINVH)*kINVH
             + ((ue - uc)*kINVH - (uc - uw)*kINVH)*kINVH;
    }
    float glx, gly;
    float lc = logf(fmaxf(cc, 1e-6f));
    if (i == 0)        { glx = (logf(fmaxf(c[rem+S],1e-6f)) - lc) * kINVH; }
    else if (i == S-1) { glx = (lc - logf(fmaxf(c[rem-S],1e-6f))) * kINVH; }
    else { glx = (logf(fmaxf(c[rem+S],1e-6f)) - logf(fmaxf(c[rem-S],1e-6f))) * kINV2H; }
    if (j == 0)        { gly = (logf(fmaxf(c[rem+1],1e-6f)) - lc) * kINVH; }
    else if (j == S-1) { gly = (lc - logf(fmaxf(c[rem-1],1e-6f))) * kINVH; }
    else { gly = (logf(fmaxf(c[rem+1],1e-6f)) - logf(fmaxf(c[rem-1],1e-6f))) * kINV2H; }
    float eta  = sqrtf(glx*glx + gly*gly + 1e-6f);
    float rhov = 1.f / (1.f + expf(-10.f * (eta - 0.5f)));
    float nhx = glx / eta, nhy = gly / eta;
    float4 b4 = ((const float4*)bb)[rem];
    f[0] = lapv; f[1] = rhov;
    f[2] = b4.y * nhx - b4.z * nhy;
    f[3] = b4.y * nhy + b4.z * nhx;
    f[4] = cc; f[5] = uc; f[6] = b4.x; f[7] = b4.w;
}

// ========== K_SETUP: 16x16 LDS-tiled cell fields + face taus + harmonic coeffs =====
// Each cell's cellfield computed ONCE (1.13x work incl. halo) instead of 3x.
__global__ __launch_bounds__(256) void k_setup(
        const float* __restrict__ coeff, const float* __restrict__ u,
        const float* __restrict__ beta,
        float* __restrict__ taux, float* __restrict__ tauyP,
        float* __restrict__ cxP, float* __restrict__ cyP) {
    __shared__ float sF[8][TS+1][TS+8];        // pad 24: <=2-way bank alias (free)
    int b  = blockIdx.x >> 10;                 // 1024 tiles per batch
    int tl = blockIdx.x & 1023;
    int i0 = (tl >> 5) << 4;
    int j0 = (tl & 31) << 4;
    int tx = threadIdx.x & 15, ty = threadIdx.x >> 4;
    const float* cB = coeff + (b << 18);
    const float* uB = u     + (b << 18);
    const float* bB = beta  + ((size_t)b << 20);

    {   // own cell
        float f[8];
        cellfield8(cB, uB, bB, i0 + ty, j0 + tx, f);
        #pragma unroll
        for (int q = 0; q < 8; ++q) sF[q][ty][tx] = f[q];
    }
    // halo: bottom row (wave 0, 16 lanes) and right col (wave 1, 16 lanes)
    if (threadIdx.x < 16 && i0 + TS < S) {
        float f[8];
        cellfield8(cB, uB, bB, i0 + TS, j0 + threadIdx.x, f);
        #pragma unroll
        for (int q = 0; q < 8; ++q) sF[q][TS][threadIdx.x] = f[q];
    }
    if (threadIdx.x >= 64 && threadIdx.x < 80 && j0 + TS < S) {
        int k = threadIdx.x - 64;
        float f[8];
        cellfield8(cB, uB, bB, i0 + k, j0 + TS, f);
        #pragma unroll
        for (int q = 0; q < 8; ++q) sF[q][k][TS] = f[q];
    }
    __syncthreads();

    int ci = i0 + ty, cj = j0 + tx;
    int rem = ci * S + cj;
    float lap0 = sF[0][ty][tx], rho0 = sF[1][ty][tx];
    float sx0  = sF[2][ty][tx], sy0  = sF[3][ty][tx];
    float c0   = sF[4][ty][tx], u0   = sF[5][ty][tx];
    float bb0  = sF[6][ty][tx], bw0  = sF[7][ty][tx];
    float rb0, nx0, ny0; geom(ci, cj, rb0, nx0, ny0);

    if (ci < S-1) {                                 // x-face: cells (ci,cj),(ci+1,cj)
        float lap1 = sF[0][ty+1][tx], rho1 = sF[1][ty+1][tx], sx1 = sF[2][ty+1][tx];
        float c1 = sF[4][ty+1][tx], u1 = sF[5][ty+1][tx];
        float bb1 = sF[6][ty+1][tx], bw1 = sF[7][ty+1][tx];
        float cx = 2.f * c1 * c0 / (c1 + c0 + 1e-6f);
        cxP[(b << 18) + rem] = cx;
        float t = 0.f;
        if (cj > 0 && cj < S-1) {
            float gux = (u1 - u0) * kINVH;
            float lgx = (lap1 - lap0) * kINVH;
            float rb1, nx1, ny1; geom(ci+1, cj, rb1, nx1, ny1);
            float abb  = 0.5f * (bb1 + bb0);
            float arho = 0.5f * (rho1 + rho0);
            float asx  = 0.5f * (sx1 + sx0);
            float arb  = 0.5f * (rb1 + rb0);
            float abx  = 0.5f * (bw1 * nx1 + bw0 * nx0);
            t = abb * kH2 * cx * lgx + arho * asx * cx * gux + arb * abx * cx * gux;
        }
        taux[b * NFACE + rem] = t;
    }
    if (cj < S-1) {                                 // y-face: cells (ci,cj),(ci,cj+1)
        float lap1 = sF[0][ty][tx+1], rho1 = sF[1][ty][tx+1], sy1 = sF[3][ty][tx+1];
        float c1 = sF[4][ty][tx+1], u1 = sF[5][ty][tx+1];
        float bb1 = sF[6][ty][tx+1], bw1 = sF[7][ty][tx+1];
        float cy = 2.f * c1 * c0 / (c1 + c0 + 1e-6f);
        cyP[(b << 18) + rem] = cy;
        float t = 0.f;
        if (ci > 0 && ci < S-1) {
            float guy = (u1 - u0) * kINVH;
            float lgy = (lap1 - lap0) * kINVH;
            float rb1, nx1, ny1; geom(ci, cj+1, rb1, nx1, ny1);
            float abb  = 0.5f * (bb1 + bb0);
            float arho = 0.5f * (rho1 + rho0);
            float asy  = 0.5f * (sy1 + sy0);
            float arb  = 0.5f * (rb1 + rb0);
            float aby  = 0.5f * (bw1 * ny1 + bw0 * ny0);
            t = abb * kH2 * cy * lgy + arho * asy * cy * guy + arb * aby * cy * guy;
        }
        tauyP[(b << 18) + rem] = t;
    }
}

// ================= K3: rhs = div(tau); r=p=rhs; x=0; rr partials (256/batch) =======
__global__ void k_rhs(const float* __restrict__ taux, const float* __restrict__ tauyP,
                      float* __restrict__ r, float* __restrict__ p, float* __restrict__ x,
                      double* __restrict__ rrPart) {
    __shared__ double lds[4];
    int t = blockIdx.x * 256 + threadIdx.x;
    int b = t >> 16;
    int rem = t & 65535;
    int i = rem >> 7;
    int j0 = (rem & 127) << 2;

    float4 o = make_float4(0.f, 0.f, 0.f, 0.f);
    float* oa = (float*)&o;
    if (i > 0 && i < S-1) {
        const float* tx  = taux  + b * NFACE;
        const float* typ = tauyP + b * NCELL;
        float4 txC = ((const float4*)tx)[i * 128 + (j0 >> 2)];
        float4 txS = ((const float4*)tx)[(i-1) * 128 + (j0 >> 2)];
        float4 tyC = ((const float4*)typ)[i * 128 + (j0 >> 2)];
        float tyW = (j0 > 0) ? typ[i * S + j0 - 1] : 0.f;
        const float* txCa = (const float*)&txC;
        const float* txSa = (const float*)&txS;
        const float* tyCa = (const float*)&tyC;
        #pragma unroll
        for (int k = 0; k < 4; ++k) {
            int j = j0 + k;
            if (j > 0 && j < S-1) {
                float tyw = (k == 0) ? tyW : tyCa[k-1];
                oa[k] = (txCa[k] - txSa[k]) * kINVH + (tyCa[k] - tyw) * kINVH;
            }
        }
    }
    ((float4*)r)[t] = o;
    ((float4*)p)[t] = o;
    ((float4*)x)[t] = make_float4(0.f, 0.f, 0.f, 0.f);
    double local = (double)oa[0]*oa[0] + (double)oa[1]*oa[1]
                 + (double)oa[2]*oa[2] + (double)oa[3]*oa[3];
    for (int off = 32; off > 0; off >>= 1) local += __shfl_down(local, off, 64);
    int lane = threadIdx.x & 63, wave = threadIdx.x >> 6;
    if (lane == 0) lds[wave] = local;
    __syncthreads();
    if (threadIdx.x == 0) rrPart[blockIdx.x] = lds[0]+lds[1]+lds[2]+lds[3];
}

// ====== K_ITER0: ap0 = A(p0); dots; rn0 from rrPart (edge-lane scalar + shfl) ======
__global__ __launch_bounds__(256, 4) void k_iter0(
        const float* __restrict__ cxP, const float* __restrict__ cyP,
        const float* __restrict__ pIn, float* __restrict__ apOut,
        const double* __restrict__ rrPart,
        double* __restrict__ dotsOut, double* __restrict__ rnOut) {
    __shared__ double lds[12];
    int t = blockIdx.x * 256 + threadIdx.x;
    int b = t >> 16;
    int rem = t & 65535;
    int i = rem >> 7;
    int j0 = (rem & 127) << 2;
    int idx = (b << 18) + (i << 9) + j0;
    int v = idx >> 2;
    int lane = threadIdx.x & 63, wave = threadIdx.x >> 6;

    // rn_0 = sum of rhs partials
    {
        double v0 = rrPart[(b << 8) + threadIdx.x];
        #pragma unroll
        for (int off = 32; off > 0; off >>= 1) v0 += __shfl_down(v0, off, 64);
        if (lane == 0) lds[wave] = v0;
    }
    __syncthreads();
    double rnCur = lds[0]+lds[1]+lds[2]+lds[3];
    __syncthreads();

    double dpap = 0.0, dapap = 0.0;
    if (i > 0 && i < S-1) {
        const float4* p4p = (const float4*)pIn;
        float4 pC4 = p4p[v], pN4 = p4p[v+128], pS4 = p4p[v-128];
        float4 cx4 = ((const float4*)cxP)[v];
        float4 cs4 = ((const float4*)cxP)[v-128];
        float4 cy4 = ((const float4*)cyP)[v];
        const float* pCa=(const float*)&pC4; const float* pNa=(const float*)&pN4;
        const float* pSa=(const float*)&pS4;
        const float* cxa=(const float*)&cx4; const float* csa=(const float*)&cs4;
        const float* cya=(const float*)&cy4;
        // cross-wave edge values: 1-lane predicated loads; rest via shfl
        float pW_l = 0.f, pE_l = 0.f, cyW_l = 0.f;
        if (lane == 0 && j0 > 0)      { pW_l = pIn[idx-1]; cyW_l = cyP[idx-1]; }
        if (lane == 63 && j0 + 4 < S) { pE_l = pIn[idx+4]; }
        float pW = __shfl_up(pCa[3], 1);   if (lane == 0)  pW = pW_l;
        float pE = __shfl_down(pCa[0], 1); if (lane == 63) pE = pE_l;
        float cyWs = __shfl_up(cy4.w, 1);  if (lane == 0)  cyWs = cyW_l;

        float apk[4];
        #pragma unroll
        for (int k = 0; k < 4; ++k) {
            int j = j0 + k;
            if (j > 0 && j < S-1) {
                float pe = (k < 3) ? pCa[k+1] : pE;
                float pw = (k > 0) ? pCa[k-1] : pW;
                float cyWk = (k > 0) ? cya[k-1] : cyWs;
                float qxp = cxa[k] * ((pNa[k] - pCa[k]) * kINVH);
                float qxm = csa[k] * ((pCa[k] - pSa[k]) * kINVH);
                float qyp = cya[k] * ((pe - pCa[k]) * kINVH);
                float qym = cyWk   * ((pCa[k] - pw) * kINVH);
                apk[k] = -((qxp - qxm) * kINVH + (qyp - qym) * kINVH);
            } else {
                apk[k] = pCa[k];               // Dirichlet (value is 0)
            }
            dpap  += (double)pCa[k] * (double)apk[k];
            dapap += (double)apk[k] * (double)apk[k];
        }
        float4 ao; ao.x=apk[0]; ao.y=apk[1]; ao.z=apk[2]; ao.w=apk[3];
        ((float4*)apOut)[v] = ao;
    } else {
        ((float4*)apOut)[v] = make_float4(0.f,0.f,0.f,0.f);
    }

    #pragma unroll
    for (int off = 32; off > 0; off >>= 1) {
        dpap  += __shfl_down(dpap,  off, 64);
        dapap += __shfl_down(dapap, off, 64);
    }
    __syncthreads();
    if (lane == 0) { lds[wave] = dpap; lds[4+wave] = dapap; }
    __syncthreads();
    if (threadIdx.x == 0) {
        double s1 = lds[0]+lds[1]+lds[2]+lds[3];
        dotsOut[blockIdx.x]          = s1;
        dotsOut[NBLK + blockIdx.x]   = s1;     // r0 == p0 -> <r,ap> == <p,ap>
        dotsOut[2*NBLK + blockIdx.x] = lds[4]+lds[5]+lds[6]+lds[7];
        if ((blockIdx.x & 255) == 0) rnOut[b] = rnCur;
    }
}

// ====== K_ITER: one steady CG iteration (edge-lane scalar + shfl halo) =============
__global__ __launch_bounds__(256, 4) void k_iter(
        const float* __restrict__ cxP, const float* __restrict__ cyP,
        const float* __restrict__ rIn,  float* __restrict__ rOut,
        const float* __restrict__ pIn,  float* __restrict__ pOut,
        const float* __restrict__ apIn, float* __restrict__ apOut,
        float* __restrict__ x,
        const double* __restrict__ dotsIn, double* __restrict__ dotsOut,
        const double* __restrict__ rnIn,  double* __restrict__ rnOut) {
    __shared__ double lds[12];
    int t = blockIdx.x * 256 + threadIdx.x;
    int b = t >> 16;
    int rem = t & 65535;
    int i = rem >> 7;
    int j0 = (rem & 127) << 2;
    int idx = (b << 18) + (i << 9) + j0;
    int v = idx >> 2;
    int lane = threadIdx.x & 63, wave = threadIdx.x >> 6;

    // ---- scalars: fused triple reduce of previous dots ----
    {
        int s = (b << 8) + threadIdx.x;
        double v0 = dotsIn[s];
        double v1 = dotsIn[NBLK + s];
        double v2 = dotsIn[2*NBLK + s];
        #pragma unroll
        for (int off = 32; off > 0; off >>= 1) {
            v0 += __shfl_down(v0, off, 64);
            v1 += __shfl_down(v1, off, 64);
            v2 += __shfl_down(v2, off, 64);
        }
        if (lane == 0) { lds[wave] = v0; lds[4+wave] = v1; lds[8+wave] = v2; }
    }
    __syncthreads();
    double pap  = lds[0]+lds[1]+lds[2]+lds[3];
    double rap  = lds[4]+lds[5]+lds[6]+lds[7];
    double apap = lds[8]+lds[9]+lds[10]+lds[11];
    double rnPrev = rnIn[b];
    float alphaF = (float)(rnPrev / fmax(pap, 1e-6));
    double aD = (double)alphaF;
    double rnCur = rnPrev - 2.0 * aD * rap + aD * aD * apap;
    float betaF = (float)(rnCur / fmax(rnPrev, 1e-6));

    double dpap = 0.0, drap = 0.0, dapap = 0.0;
    if (i > 0 && i < S-1) {
        const float4* r4p = (const float4*)rIn;
        const float4* p4p = (const float4*)pIn;
        const float4* a4p = (const float4*)apIn;
        float4 rC4=r4p[v], rN4=r4p[v+128], rS4=r4p[v-128];
        float4 pC4=p4p[v], pN4=p4p[v+128], pS4=p4p[v-128];
        float4 aC4=a4p[v], aN4=a4p[v+128], aS4=a4p[v-128];
        float4 cx4 = ((const float4*)cxP)[v];
        float4 cs4 = ((const float4*)cxP)[v-128];
        float4 cy4 = ((const float4*)cyP)[v];
        const float* rCa=(const float*)&rC4; const float* rNa=(const float*)&rN4;
        const float* rSa=(const float*)&rS4;
        const float* pCa=(const float*)&pC4; const float* pNa=(const float*)&pN4;
        const float* pSa=(const float*)&pS4;
        const float* aCa=(const float*)&aC4; const float* aNa=(const float*)&aN4;
        const float* aSa=(const float*)&aS4;
        const float* cxa=(const float*)&cx4; const float* csa=(const float*)&cs4;
        const float* cya=(const float*)&cy4;
        // cross-wave edge values: 1-lane predicated loads; rest via shfl
        float rW_l=0.f, pW_l=0.f, aW_l=0.f, cyW_l=0.f, rE_l=0.f, pE_l=0.f, aE_l=0.f;
        if (lane == 0 && j0 > 0) {
            rW_l = rIn[idx-1]; pW_l = pIn[idx-1]; aW_l = apIn[idx-1]; cyW_l = cyP[idx-1];
        }
        if (lane == 63 && j0 + 4 < S) {
            rE_l = rIn[idx+4]; pE_l = pIn[idx+4]; aE_l = apIn[idx+4];
        }

        // x += alpha * p_old
        float4 x4 = ((const float4*)x)[v];
        x4.x += alphaF * pCa[0]; x4.y += alphaF * pCa[1];
        x4.z += alphaF * pCa[2]; x4.w += alphaF * pCa[3];
        ((float4*)x)[v] = x4;

        float pnC[4], pnN[4], pnS[4], rnC[4];
        #pragma unroll
        for (int k = 0; k < 4; ++k) {
            rnC[k]     = rCa[k] - alphaF * aCa[k];
            pnC[k]     = rnC[k] + betaF * pCa[k];
            float rnNk = rNa[k] - alphaF * aNa[k];
            pnN[k]     = rnNk   + betaF * pNa[k];
            float rnSk = rSa[k] - alphaF * aSa[k];
            pnS[k]     = rnSk   + betaF * pSa[k];
        }
        // W/E halo of pn: shuffle from neighbor lanes (bit-identical expressions),
        // cross-wave edge from the 1-lane loads
        float pnW_l = (rW_l - alphaF * aW_l) + betaF * pW_l;
        float pnE_l = (rE_l - alphaF * aE_l) + betaF * pE_l;
        float pnW = __shfl_up(pnC[3], 1);   if (lane == 0)  pnW = pnW_l;
        float pnE = __shfl_down(pnC[0], 1); if (lane == 63) pnE = pnE_l;
        float cyWs = __shfl_up(cy4.w, 1);   if (lane == 0)  cyWs = cyW_l;

        float apk[4];
        #pragma unroll
        for (int k = 0; k < 4; ++k) {
            int j = j0 + k;
            if (j > 0 && j < S-1) {
                float pe = (k < 3) ? pnC[k+1] : pnE;
                float pw = (k > 0) ? pnC[k-1] : pnW;
                float cyWk = (k > 0) ? cya[k-1] : cyWs;
                float qxp = cxa[k] * ((pnN[k] - pnC[k]) * kINVH);
                float qxm = csa[k] * ((pnC[k] - pnS[k]) * kINVH);
                float qyp = cya[k] * ((pe - pnC[k]) * kINVH);
                float qym = cyWk   * ((pnC[k] - pw) * kINVH);
                apk[k] = -((qxp - qxm) * kINVH + (qyp - qym) * kINVH);
            } else {
                apk[k] = pnC[k];               // Dirichlet (value is 0)
            }
            dpap  += (double)pnC[k] * (double)apk[k];
            drap  += (double)rnC[k] * (double)apk[k];
            dapap += (double)apk[k] * (double)apk[k];
        }

        float4 ao; ao.x=apk[0]; ao.y=apk[1]; ao.z=apk[2]; ao.w=apk[3];
        float4 ro; ro.x=rnC[0]; ro.y=rnC[1]; ro.z=rnC[2]; ro.w=rnC[3];
        float4 po; po.x=pnC[0]; po.y=pnC[1]; po.z=pnC[2]; po.w=pnC[3];
        ((float4*)apOut)[v] = ao;
        ((float4*)rOut)[v] = ro;
        ((float4*)pOut)[v] = po;
    } else {
        float4 z = make_float4(0.f,0.f,0.f,0.f);
        ((float4*)apOut)[v] = z;
        ((float4*)rOut)[v] = z;
        ((float4*)pOut)[v] = z;
    }

    // ---- fused triple block-sum of new dots ----
    #pragma unroll
    for (int off = 32; off > 0; off >>= 1) {
        dpap  += __shfl_down(dpap,  off, 64);
        drap  += __shfl_down(drap,  off, 64);
        dapap += __shfl_down(dapap, off, 64);
    }
    __syncthreads();
    if (lane == 0) { lds[wave] = dpap; lds[4+wave] = drap; lds[8+wave] = dapap; }
    __syncthreads();
    if (threadIdx.x == 0) {
        dotsOut[blockIdx.x]          = lds[0]+lds[1]+lds[2]+lds[3];
        dotsOut[NBLK + blockIdx.x]   = lds[4]+lds[5]+lds[6]+lds[7];
        dotsOut[2*NBLK + blockIdx.x] = lds[8]+lds[9]+lds[10]+lds[11];
        if ((blockIdx.x & 255) == 0) rnOut[b] = rnCur;
    }
}

// ====== KF: final alpha; out = zb(u + x + alpha*p_19) ==============================
__global__ void k_fin(const float* __restrict__ u, const float* __restrict__ p,
                      float* __restrict__ out,
                      const double* __restrict__ dotsIn, const double* __restrict__ rnIn) {
    __shared__ double lds[4];
    int t = blockIdx.x * 256 + threadIdx.x;
    int b = t >> 16;
    int lane = threadIdx.x & 63, wave = threadIdx.x >> 6;
    {
        double v0 = dotsIn[(b << 8) + threadIdx.x];
        #pragma unroll
        for (int off = 32; off > 0; off >>= 1) v0 += __shfl_down(v0, off, 64);
        if (lane == 0) lds[wave] = v0;
    }
    __syncthreads();
    double pap = lds[0]+lds[1]+lds[2]+lds[3];
    float alpha = (float)(rnIn[b] / fmax(pap, 1e-6));
    int rem = t & 65535;
    int i = rem >> 7;
    int j0 = (rem & 127) << 2;
    float4 o = make_float4(0.f,0.f,0.f,0.f);
    if (i > 0 && i < S-1) {
        float4 u4 = ((const float4*)u)[t];
        float4 x4 = ((const float4*)out)[t];
        float4 p4 = ((const float4*)p)[t];
        const float* ua=(const float*)&u4; const float* xa=(const float*)&x4;
        const float* pa=(const float*)&p4; float* oa=(float*)&o;
        #pragma unroll
        for (int k = 0; k < 4; ++k) {
            int j = j0 + k;
            if (j > 0 && j < S-1) oa[k] = ua[k] + xa[k] + alpha * pa[k];
        }
    }
    ((float4*)out)[t] = o;
}

extern "C" void kernel_launch(void* const* d_in, const int* in_sizes, int n_in,
                              void* d_out, int out_size, void* d_ws, size_t ws_size,
                              hipStream_t stream) {
    const float* coeff = (const float*)d_in[0];
    const float* u     = (const float*)d_in[1];
    const float* beta  = (const float*)d_in[2];
    float* x = (float*)d_out;

    // ws: 8 cell-sized float arrays (64 MB) + double partials.
    // Overlays: taux->apB, tauyP->apA (consumed by k_rhs/k_iter0 before overwritten).
    float* fb  = (float*)d_ws;
    float* rA  = fb;
    float* rB  = rA  + NTOT;
    float* pA  = rB  + NTOT;
    float* pB  = pA  + NTOT;
    float* apA = pB  + NTOT;     // = tauyP during setup
    float* apB = apA + NTOT;     // = taux  during setup
    float* cxP = apB + NTOT;
    float* cyP = cxP + NTOT;
    double* rrPart = (double*)(cyP + NTOT);   // NBLK
    double* setA   = rrPart + NBLK;           // 3*NBLK
    double* setB   = setA + 3*NBLK;
    double* rnA    = setB + 3*NBLK;           // Bsz
    double* rnB    = rnA + Bsz;

    dim3 blk(256);

    k_setup<<<8192, blk, 0, stream>>>(coeff, u, beta,
                                      apB /*taux*/, apA /*tauyP*/, cxP, cyP);
    k_rhs<<<NBLK, blk, 0, stream>>>(apB, apA, rA, pA, x, rrPart);
    k_iter0<<<NBLK, blk, 0, stream>>>(cxP, cyP, pA, apA, rrPart, setA, rnA);

    const float *ri=rA, *pi=pA, *ai=apA;
    float *ro=rB, *po=pB, *ao=apB;
    const double *dIn=setA, *rnIn=rnA;
    double *dOut=setB, *rnOut=rnB;
    for (int it = 1; it < CG_ITERS; ++it) {
        k_iter<<<NBLK, blk, 0, stream>>>(cxP, cyP, ri, ro, pi, po, ai, ao,
                                         x, dIn, dOut, rnIn, rnOut);
        { const float* s=ri; ri=ro; ro=(float*)s; }
        { const float* s=pi; pi=po; po=(float*)s; }
        { const float* s=ai; ai=ao; ao=(float*)s; }
        { const double* s=dIn; dIn=dOut; dOut=(double*)s; }
        { const double* s=rnIn; rnIn=rnOut; rnOut=(double*)s; }
    }

    k_fin<<<NBLK, blk, 0, stream>>>(u, pi, x, dIn, rnIn);
}

// Round 9
// 503.531 us; speedup vs baseline: 1.2094x; 1.0454x over previous
//
#include <hip/hip_runtime.h>
#include <math.h>

// Problem constants (match reference)
#define S     512
#define Bsz   8
#define NCELL (S*S)              // 262144 = 2^18
#define NTOT  (Bsz*NCELL)        // 2097152
#define NFACE ((S-1)*S)          // 261632
#define CG_ITERS 20
#define NBLK  2048               // loop grid: 256 blocks/batch (4 rows x 256 cols each)
#define TS    16                 // k_setup tile

__device__ __constant__ float kINVH  = 511.0f;     // 1/h
__device__ __constant__ float kINV2H = 255.5f;
__device__ __constant__ float kH2    = (float)((1.0/511.0)*(1.0/511.0));

// ---------------- geometry (replicates numpy grid_helpers bit-exactly in double) ----
__device__ __forceinline__ void geom(int i, int j, float& rhob, float& bnx, float& bny) {
    double gx = (i == S-1) ? 1.0 : (double)i * (1.0/511.0);
    double gy = (j == S-1) ? 1.0 : (double)j * (1.0/511.0);
    double v0 = gx, v1 = 1.0 - gx, v2 = gy, v3 = 1.0 - gy;
    double m = v0; int am = 0;
    if (v1 < m) { m = v1; am = 1; }   // strict '<' == np.argmin first-min-wins
    if (v2 < m) { m = v2; am = 2; }
    if (v3 < m) { m = v3; am = 3; }
    float d = (float)m;
    rhob = expf(-(d*d) / 0.0225f);
    bnx = (am == 0) ? -1.f : (am == 1) ? 1.f : 0.f;
    bny = (am == 2) ? -1.f : (am == 3) ? 1.f : 0.f;
}

// ---- per-cell fields; expressions identical to R8 -> bit-identical values ---------
__device__ __forceinline__ void cellfield8(const float* __restrict__ c,
                                           const float* __restrict__ uu,
                                           const float* __restrict__ bb,
                                           int i, int j, float* f) {
    int rem = i * S + j;
    float cc = c[rem];
    float uc = uu[rem];
    float lapv = 0.f;
    if (i > 0 && i < S-1 && j > 0 && j < S-1) {
        float un = uu[rem + S], us = uu[rem - S];
        float ue = uu[rem + 1], uw = uu[rem - 1];
        lapv = ((un - uc)*kINVH - (uc - us)*kINVH)*kINVH
             + ((ue - uc)*kINVH - (uc - uw)*kINVH)*kINVH;
    }
    float glx, gly;
    float lc = logf(fmaxf(cc, 1e-6f));
    if (i == 0)        { glx = (logf(fmaxf(c[rem+S],1e-6f)) - lc) * kINVH; }
    else if (i == S-1) { glx = (lc - logf(fmaxf(c[rem-S],1e-6f))) * kINVH; }
    else { glx = (logf(fmaxf(c[rem+S],1e-6f)) - logf(fmaxf(c[rem-S],1e-6f))) * kINV2H; }
    if (j == 0)        { gly = (logf(fmaxf(c[rem+1],1e-6f)) - lc) * kINVH; }
    else if (j == S-1) { gly = (lc - logf(fmaxf(c[rem-1],1e-6f))) * kINVH; }
    else { gly = (logf(fmaxf(c[rem+1],1e-6f)) - logf(fmaxf(c[rem-1],1e-6f))) * kINV2H; }
    float eta  = sqrtf(glx*glx + gly*gly + 1e-6f);
    float rhov = 1.f / (1.f + expf(-10.f * (eta - 0.5f)));
    float nhx = glx / eta, nhy = gly / eta;
    float4 b4 = ((const float4*)bb)[rem];
    f[0] = lapv; f[1] = rhov;
    f[2] = b4.y * nhx - b4.z * nhy;
    f[3] = b4.y * nhy + b4.z * nhx;
    f[4] = cc; f[5] = uc; f[6] = b4.x; f[7] = b4.w;
}

// ========== K_SETUP: 16x16 LDS-tiled cell fields + face taus + harmonic coeffs =====
__global__ __launch_bounds__(256) void k_setup(
        const float* __restrict__ coeff, const float* __restrict__ u,
        const float* __restrict__ beta,
        float* __restrict__ taux, float* __restrict__ tauyP,
        float* __restrict__ cxP, float* __restrict__ cyP) {
    __shared__ float sF[8][TS+1][TS+8];
    int b  = blockIdx.x >> 10;
    int tl = blockIdx.x & 1023;
    int i0 = (tl >> 5) << 4;
    int j0 = (tl & 31) << 4;
    int tx = threadIdx.x & 15, ty = threadIdx.x >> 4;
    const float* cB = coeff + (b << 18);
    const float* uB = u     + (b << 18);
    const float* bB = beta  + ((size_t)b << 20);

    {   float f[8];
        cellfield8(cB, uB, bB, i0 + ty, j0 + tx, f);
        #pragma unroll
        for (int q = 0; q < 8; ++q) sF[q][ty][tx] = f[q];
    }
    if (threadIdx.x < 16 && i0 + TS < S) {
        float f[8];
        cellfield8(cB, uB, bB, i0 + TS, j0 + threadIdx.x, f);
        #pragma unroll
        for (int q = 0; q < 8; ++q) sF[q][TS][threadIdx.x] = f[q];
    }
    if (threadIdx.x >= 64 && threadIdx.x < 80 && j0 + TS < S) {
        int k = threadIdx.x - 64;
        float f[8];
        cellfield8(cB, uB, bB, i0 + k, j0 + TS, f);
        #pragma unroll
        for (int q = 0; q < 8; ++q) sF[q][k][TS] = f[q];
    }
    __syncthreads();

    int ci = i0 + ty, cj = j0 + tx;
    int rem = ci * S + cj;
    float lap0 = sF[0][ty][tx], rho0 = sF[1][ty][tx];
    float sx0  = sF[2][ty][tx], sy0  = sF[3][ty][tx];
    float c0   = sF[4][ty][tx], u0   = sF[5][ty][tx];
    float bb0  = sF[6][ty][tx], bw0  = sF[7][ty][tx];
    float rb0, nx0, ny0; geom(ci, cj, rb0, nx0, ny0);

    if (ci < S-1) {
        float lap1 = sF[0][ty+1][tx], rho1 = sF[1][ty+1][tx], sx1 = sF[2][ty+1][tx];
        float c1 = sF[4][ty+1][tx], u1 = sF[5][ty+1][tx];
        float bb1 = sF[6][ty+1][tx], bw1 = sF[7][ty+1][tx];
        float cx = 2.f * c1 * c0 / (c1 + c0 + 1e-6f);
        cxP[(b << 18) + rem] = cx;
        float t = 0.f;
        if (cj > 0 && cj < S-1) {
            float gux = (u1 - u0) * kINVH;
            float lgx = (lap1 - lap0) * kINVH;
            float rb1, nx1, ny1; geom(ci+1, cj, rb1, nx1, ny1);
            float abb  = 0.5f * (bb1 + bb0);
            float arho = 0.5f * (rho1 + rho0);
            float asx  = 0.5f * (sx1 + sx0);
            float arb  = 0.5f * (rb1 + rb0);
            float abx  = 0.5f * (bw1 * nx1 + bw0 * nx0);
            t = abb * kH2 * cx * lgx + arho * asx * cx * gux + arb * abx * cx * gux;
        }
        taux[b * NFACE + rem] = t;
    }
    if (cj < S-1) {
        float lap1 = sF[0][ty][tx+1], rho1 = sF[1][ty][tx+1], sy1 = sF[3][ty][tx+1];
        float c1 = sF[4][ty][tx+1], u1 = sF[5][ty][tx+1];
        float bb1 = sF[6][ty][tx+1], bw1 = sF[7][ty][tx+1];
        float cy = 2.f * c1 * c0 / (c1 + c0 + 1e-6f);
        cyP[(b << 18) + rem] = cy;
        float t = 0.f;
        if (ci > 0 && ci < S-1) {
            float guy = (u1 - u0) * kINVH;
            float lgy = (lap1 - lap0) * kINVH;
            float rb1, nx1, ny1; geom(ci, cj+1, rb1, nx1, ny1);
            float abb  = 0.5f * (bb1 + bb0);
            float arho = 0.5f * (rho1 + rho0);
            float asy  = 0.5f * (sy1 + sy0);
            float arb  = 0.5f * (rb1 + rb0);
            float aby  = 0.5f * (bw1 * ny1 + bw0 * ny0);
            t = abb * kH2 * cy * lgy + arho * asy * cy * guy + arb * aby * cy * guy;
        }
        tauyP[(b << 18) + rem] = t;
    }
}

// ====== K_RHS0: rhs=div(tau) (incl. halo recompute); p0=r0=rhs; x=0; ap0=A(p0);
//        4 dot-partial slots: pap, rap(=pap), apap, rr ==============================
__global__ __launch_bounds__(256, 4) void k_rhs0(
        const float* __restrict__ taux, const float* __restrict__ tyP,
        const float* __restrict__ cxP, const float* __restrict__ cyP,
        float* __restrict__ p0, float* __restrict__ ap, float* __restrict__ x,
        double* __restrict__ dotsOut) {
    __shared__ double lds[16];
    int bid = blockIdx.x;
    int b   = bid >> 8;
    int loc = bid & 255;
    int rg  = loc >> 1, jh = loc & 1;
    int w   = threadIdx.x >> 6, lane = threadIdx.x & 63;
    int i   = (rg << 2) + w;
    int j0  = (jh << 8) + (lane << 2);
    int v   = ((b << 18) + (i << 9) + j0) >> 2;
    const float* txB = taux + b * NFACE;
    const float* tyB = tyP  + (b << 18);
    float4 z4 = make_float4(0.f,0.f,0.f,0.f);

    // tau loads (guarded)
    float4 txm2 = (i >= 2)   ? *((const float4*)(txB + ((i-2)<<9) + j0)) : z4;
    float4 txm1 = (i >= 1)   ? *((const float4*)(txB + ((i-1)<<9) + j0)) : z4;
    float4 tx0  = (i <= 510) ? *((const float4*)(txB + (i<<9) + j0))     : z4;
    float4 txp1 = (i <= 509) ? *((const float4*)(txB + ((i+1)<<9) + j0)) : z4;
    float4 tym1 = (i >= 1)   ? *((const float4*)(tyB + ((i-1)<<9) + j0)) : z4;
    float4 ty0  =              *((const float4*)(tyB + (i<<9) + j0));
    float4 typ1 = (i <= 510) ? *((const float4*)(tyB + ((i+1)<<9) + j0)) : z4;
    const float* txm2a=(const float*)&txm2; const float* txm1a=(const float*)&txm1;
    const float* tx0a=(const float*)&tx0;   const float* txp1a=(const float*)&txp1;
    const float* tym1a=(const float*)&tym1; const float* ty0a=(const float*)&ty0;
    const float* typ1a=(const float*)&typ1;

    // per-row west tau via shfl (lane 0: global)
    float tyWS = __shfl_up(tym1.w, 1), tyWC = __shfl_up(ty0.w, 1), tyWN = __shfl_up(typ1.w, 1);
    if (lane == 0 && j0 > 0) {
        tyWS = (i >= 1)   ? tyB[((i-1)<<9) + j0 - 1] : 0.f;
        tyWC =              tyB[(i<<9) + j0 - 1];
        tyWN = (i <= 510) ? tyB[((i+1)<<9) + j0 - 1] : 0.f;
    }

    // rhs rows S(i-1), C(i), N(i+1) — bit-identical to the old k_rhs formula
    float rhsS[4], rhsC[4], rhsN[4];
    #pragma unroll
    for (int k = 0; k < 4; ++k) {
        int j = j0 + k;
        bool jint = (j > 0 && j < S-1);
        float twS = (k == 0) ? tyWS : tym1a[k-1];
        float twC = (k == 0) ? tyWC : ty0a[k-1];
        float twN = (k == 0) ? tyWN : typ1a[k-1];
        rhsS[k] = (i-1 > 0 && i-1 < S-1 && jint)
                ? (txm1a[k]-txm2a[k])*kINVH + (tym1a[k]-twS)*kINVH : 0.f;
        rhsC[k] = (i > 0 && i < S-1 && jint)
                ? (tx0a[k]-txm1a[k])*kINVH + (ty0a[k]-twC)*kINVH : 0.f;
        rhsN[k] = (i+1 > 0 && i+1 < S-1 && jint)
                ? (txp1a[k]-tx0a[k])*kINVH + (typ1a[k]-twN)*kINVH : 0.f;
    }
    // W/E of rhsC via shfl; edge lanes recompute from tau
    float rhsW_l = 0.f, rhsE_l = 0.f;
    if (lane == 0 && j0 > 0) {
        int jw = j0 - 1;
        if (i > 0 && i < S-1 && jw > 0 && jw < S-1)
            rhsW_l = (txB[(i<<9)+jw]-txB[((i-1)<<9)+jw])*kINVH
                   + (tyB[(i<<9)+jw]-tyB[(i<<9)+jw-1])*kINVH;
    }
    if (lane == 63 && j0 + 4 < S) {
        int je = j0 + 4;
        if (i > 0 && i < S-1 && je > 0 && je < S-1)
            rhsE_l = (txB[(i<<9)+je]-txB[((i-1)<<9)+je])*kINVH
                   + (tyB[(i<<9)+je]-tyB[(i<<9)+je-1])*kINVH;
    }
    float pW = __shfl_up(rhsC[3], 1);   if (lane == 0)  pW = rhsW_l;
    float pE = __shfl_down(rhsC[0], 1); if (lane == 63) pE = rhsE_l;

    double dpap = 0.0, dapap = 0.0, drr = 0.0;
    float apk[4] = {0.f,0.f,0.f,0.f};
    if (i > 0 && i < S-1) {
        float4 cx4 = ((const float4*)cxP)[v];
        float4 cs4 = ((const float4*)cxP)[v-128];
        float4 cy4 = ((const float4*)cyP)[v];
        const float* cxa=(const float*)&cx4; const float* csa=(const float*)&cs4;
        const float* cya=(const float*)&cy4;
        float cyWs = __shfl_up(cy4.w, 1);
        if (lane == 0 && j0 > 0) cyWs = cyP[(b<<18) + (i<<9) + j0 - 1];
        else if (lane == 0) cyWs = 0.f;
        #pragma unroll
        for (int k = 0; k < 4; ++k) {
            int j = j0 + k;
            if (j > 0 && j < S-1) {
                float pe = (k < 3) ? rhsC[k+1] : pE;
                float pw = (k > 0) ? rhsC[k-1] : pW;
                float cyWk = (k > 0) ? cya[k-1] : cyWs;
                float qxp = cxa[k] * ((rhsN[k] - rhsC[k]) * kINVH);
                float qxm = csa[k] * ((rhsC[k] - rhsS[k]) * kINVH);
                float qyp = cya[k] * ((pe - rhsC[k]) * kINVH);
                float qym = cyWk   * ((rhsC[k] - pw) * kINVH);
                apk[k] = -((qxp - qxm) * kINVH + (qyp - qym) * kINVH);
            } else {
                apk[k] = rhsC[k];              // Dirichlet (value is 0)
            }
            dpap  += (double)rhsC[k] * (double)apk[k];
            dapap += (double)apk[k] * (double)apk[k];
            drr   += (double)rhsC[k] * (double)rhsC[k];
        }
    }
    float4 po; po.x=rhsC[0]; po.y=rhsC[1]; po.z=rhsC[2]; po.w=rhsC[3];
    float4 ao; ao.x=apk[0]; ao.y=apk[1]; ao.z=apk[2]; ao.w=apk[3];
    ((float4*)p0)[v] = po;
    ((float4*)ap)[v] = ao;
    ((float4*)x)[v]  = z4;

    #pragma unroll
    for (int off = 32; off > 0; off >>= 1) {
        dpap  += __shfl_down(dpap,  off, 64);
        dapap += __shfl_down(dapap, off, 64);
        drr   += __shfl_down(drr,   off, 64);
    }
    if (lane == 0) { lds[w] = dpap; lds[4+w] = dapap; lds[8+w] = drr; }
    __syncthreads();
    if (threadIdx.x == 0) {
        double s1 = lds[0]+lds[1]+lds[2]+lds[3];
        dotsOut[bid]          = s1;
        dotsOut[NBLK + bid]   = s1;            // r0 == p0
        dotsOut[2*NBLK + bid] = lds[4]+lds[5]+lds[6]+lds[7];
        dotsOut[3*NBLK + bid] = lds[8]+lds[9]+lds[10]+lds[11];
    }
}

// ====== K_ITER: one steady CG iteration (4 rows x 256 cols per block) ==============
__global__ __launch_bounds__(256, 4) void k_iter(
        const float* __restrict__ cxP, const float* __restrict__ cyP,
        const float* __restrict__ rIn,  float* __restrict__ rOut,
        const float* __restrict__ pIn,  float* __restrict__ pOut,
        const float* __restrict__ apIn, float* __restrict__ apOut,
        float* __restrict__ x,
        const double* __restrict__ dotsIn, double* __restrict__ dotsOut,
        const double* __restrict__ rnIn,  double* __restrict__ rnOut, int first) {
    __shared__ double lds[16];
    int bid = blockIdx.x;
    int b   = bid >> 8;
    int loc = bid & 255;
    int rg  = loc >> 1, jh = loc & 1;
    int w   = threadIdx.x >> 6, lane = threadIdx.x & 63;
    int i   = (rg << 2) + w;
    int j0  = (jh << 8) + (lane << 2);
    int idx = (b << 18) + (i << 9) + j0;
    int v   = idx >> 2;

    // ---- scalars: fused reduce of previous dot partials ----
    {
        int s = (b << 8) + threadIdx.x;
        double v0 = dotsIn[s];
        double v1 = dotsIn[NBLK + s];
        double v2 = dotsIn[2*NBLK + s];
        double v3 = first ? dotsIn[3*NBLK + s] : 0.0;
        #pragma unroll
        for (int off = 32; off > 0; off >>= 1) {
            v0 += __shfl_down(v0, off, 64);
            v1 += __shfl_down(v1, off, 64);
            v2 += __shfl_down(v2, off, 64);
            v3 += __shfl_down(v3, off, 64);
        }
        if (lane == 0) { lds[w] = v0; lds[4+w] = v1; lds[8+w] = v2; lds[12+w] = v3; }
    }
    __syncthreads();
    double pap  = lds[0]+lds[1]+lds[2]+lds[3];
    double rap  = lds[4]+lds[5]+lds[6]+lds[7];
    double apap = lds[8]+lds[9]+lds[10]+lds[11];
    double rnPrev = first ? (lds[12]+lds[13]+lds[14]+lds[15]) : rnIn[b];
    float alphaF = (float)(rnPrev / fmax(pap, 1e-6));
    double aD = (double)alphaF;
    double rnCur = rnPrev - 2.0 * aD * rap + aD * aD * apap;
    float betaF = (float)(rnCur / fmax(rnPrev, 1e-6));

    double dpap = 0.0, drap = 0.0, dapap = 0.0;
    if (i > 0 && i < S-1) {
        const float4* r4p = (const float4*)rIn;
        const float4* p4p = (const float4*)pIn;
        const float4* a4p = (const float4*)apIn;
        float4 rC4=r4p[v], rN4=r4p[v+128], rS4=r4p[v-128];
        float4 pC4=p4p[v], pN4=p4p[v+128], pS4=p4p[v-128];
        float4 aC4=a4p[v], aN4=a4p[v+128], aS4=a4p[v-128];
        float4 cx4 = ((const float4*)cxP)[v];
        float4 cs4 = ((const float4*)cxP)[v-128];
        float4 cy4 = ((const float4*)cyP)[v];
        const float* rCa=(const float*)&rC4; const float* rNa=(const float*)&rN4;
        const float* rSa=(const float*)&rS4;
        const float* pCa=(const float*)&pC4; const float* pNa=(const float*)&pN4;
        const float* pSa=(const float*)&pS4;
        const float* aCa=(const float*)&aC4; const float* aNa=(const float*)&aN4;
        const float* aSa=(const float*)&aS4;
        const float* cxa=(const float*)&cx4; const float* csa=(const float*)&cs4;
        const float* cya=(const float*)&cy4;
        float rW_l=0.f, pW_l=0.f, aW_l=0.f, cyW_l=0.f, rE_l=0.f, pE_l=0.f, aE_l=0.f;
        if (lane == 0 && j0 > 0) {
            rW_l = rIn[idx-1]; pW_l = pIn[idx-1]; aW_l = apIn[idx-1]; cyW_l = cyP[idx-1];
        }
        if (lane == 63 && j0 + 4 < S) {
            rE_l = rIn[idx+4]; pE_l = pIn[idx+4]; aE_l = apIn[idx+4];
        }

        // x += alpha * p_old
        float4 x4 = ((const float4*)x)[v];
        x4.x += alphaF * pCa[0]; x4.y += alphaF * pCa[1];
        x4.z += alphaF * pCa[2]; x4.w += alphaF * pCa[3];
        ((float4*)x)[v] = x4;

        float pnC[4], pnN[4], pnS[4], rnC[4];
        #pragma unroll
        for (int k = 0; k < 4; ++k) {
            rnC[k]     = rCa[k] - alphaF * aCa[k];
            pnC[k]     = rnC[k] + betaF * pCa[k];
            float rnNk = rNa[k] - alphaF * aNa[k];
            pnN[k]     = rnNk   + betaF * pNa[k];
            float rnSk = rSa[k] - alphaF * aSa[k];
            pnS[k]     = rnSk   + betaF * pSa[k];
        }
        float pnW_l = (rW_l - alphaF * aW_l) + betaF * pW_l;
        float pnE_l = (rE_l - alphaF * aE_l) + betaF * pE_l;
        float pnW = __shfl_up(pnC[3], 1);   if (lane == 0)  pnW = pnW_l;
        float pnE = __shfl_down(pnC[0], 1); if (lane == 63) pnE = pnE_l;
        float cyWs = __shfl_up(cy4.w, 1);   if (lane == 0)  cyWs = cyW_l;

        float apk[4];
        #pragma unroll
        for (int k = 0; k < 4; ++k) {
            int j = j0 + k;
            if (j > 0 && j < S-1) {
                float pe = (k < 3) ? pnC[k+1] : pnE;
                float pw = (k > 0) ? pnC[k-1] : pnW;
                float cyWk = (k > 0) ? cya[k-1] : cyWs;
                float qxp = cxa[k] * ((pnN[k] - pnC[k]) * kINVH);
                float qxm = csa[k] * ((pnC[k] - pnS[k]) * kINVH);
                float qyp = cya[k] * ((pe - pnC[k]) * kINVH);
                float qym = cyWk   * ((pnC[k] - pw) * kINVH);
                apk[k] = -((qxp - qxm) * kINVH + (qyp - qym) * kINVH);
            } else {
                apk[k] = pnC[k];               // Dirichlet (value is 0)
            }
            dpap  += (double)pnC[k] * (double)apk[k];
            drap  += (double)rnC[k] * (double)apk[k];
            dapap += (double)apk[k] * (double)apk[k];
        }

        float4 ao; ao.x=apk[0]; ao.y=apk[1]; ao.z=apk[2]; ao.w=apk[3];
        float4 ro; ro.x=rnC[0]; ro.y=rnC[1]; ro.z=rnC[2]; ro.w=rnC[3];
        float4 po; po.x=pnC[0]; po.y=pnC[1]; po.z=pnC[2]; po.w=pnC[3];
        ((float4*)apOut)[v] = ao;
        ((float4*)rOut)[v] = ro;
        ((float4*)pOut)[v] = po;
    } else {
        float4 z = make_float4(0.f,0.f,0.f,0.f);
        ((float4*)apOut)[v] = z;
        ((float4*)rOut)[v] = z;
        ((float4*)pOut)[v] = z;
    }

    #pragma unroll
    for (int off = 32; off > 0; off >>= 1) {
        dpap  += __shfl_down(dpap,  off, 64);
        drap  += __shfl_down(drap,  off, 64);
        dapap += __shfl_down(dapap, off, 64);
    }
    __syncthreads();
    if (lane == 0) { lds[w] = dpap; lds[4+w] = drap; lds[8+w] = dapap; }
    __syncthreads();
    if (threadIdx.x == 0) {
        dotsOut[bid]          = lds[0]+lds[1]+lds[2]+lds[3];
        dotsOut[NBLK + bid]   = lds[4]+lds[5]+lds[6]+lds[7];
        dotsOut[2*NBLK + bid] = lds[8]+lds[9]+lds[10]+lds[11];
        if (loc == 0) rnOut[b] = rnCur;
    }
}

// ====== KF: final alpha; out = zb(u + x + alpha*p_19) ==============================
__global__ void k_fin(const float* __restrict__ u, const float* __restrict__ p,
                      float* __restrict__ out,
                      const double* __restrict__ dotsIn, const double* __restrict__ rnIn) {
    __shared__ double lds[4];
    int t = blockIdx.x * 256 + threadIdx.x;
    int b = t >> 16;
    int lane = threadIdx.x & 63, wave = threadIdx.x >> 6;
    {
        double v0 = dotsIn[(b << 8) + threadIdx.x];
        #pragma unroll
        for (int off = 32; off > 0; off >>= 1) v0 += __shfl_down(v0, off, 64);
        if (lane == 0) lds[wave] = v0;
    }
    __syncthreads();
    double pap = lds[0]+lds[1]+lds[2]+lds[3];
    float alpha = (float)(rnIn[b] / fmax(pap, 1e-6));
    int rem = t & 65535;
    int i = rem >> 7;
    int j0 = (rem & 127) << 2;
    float4 o = make_float4(0.f,0.f,0.f,0.f);
    if (i > 0 && i < S-1) {
        float4 u4 = ((const float4*)u)[t];
        float4 x4 = ((const float4*)out)[t];
        float4 p4 = ((const float4*)p)[t];
        const float* ua=(const float*)&u4; const float* xa=(const float*)&x4;
        const float* pa=(const float*)&p4; float* oa=(float*)&o;
        #pragma unroll
        for (int k = 0; k < 4; ++k) {
            int j = j0 + k;
            if (j > 0 && j < S-1) oa[k] = ua[k] + xa[k] + alpha * pa[k];
        }
    }
    ((float4*)out)[t] = o;
}

extern "C" void kernel_launch(void* const* d_in, const int* in_sizes, int n_in,
                              void* d_out, int out_size, void* d_ws, size_t ws_size,
                              hipStream_t stream) {
    const float* coeff = (const float*)d_in[0];
    const float* u     = (const float*)d_in[1];
    const float* beta  = (const float*)d_in[2];
    float* x = (float*)d_out;

    float* fb  = (float*)d_ws;
    float* rA  = fb;
    float* rB  = rA  + NTOT;
    float* pA  = rB  + NTOT;
    float* pB  = pA  + NTOT;
    float* apA = pB  + NTOT;     // = tauyP during setup
    float* apB = apA + NTOT;     // = taux  during setup
    float* cxP = apB + NTOT;
    float* cyP = cxP + NTOT;
    double* setA = (double*)(cyP + NTOT);     // 4*NBLK
    double* setB = setA + 4*NBLK;             // 4*NBLK (slot3 unused by steady)
    double* rnA  = setB + 4*NBLK;             // Bsz
    double* rnB  = rnA + Bsz;

    dim3 blk(256);

    k_setup<<<8192, blk, 0, stream>>>(coeff, u, beta,
                                      apB /*taux*/, apA /*tauyP*/, cxP, cyP);
    // rhs + iteration-0 apply fused: p0=r0 -> pA, ap0 -> rB, dots(4 slots) -> setA
    k_rhs0<<<NBLK, blk, 0, stream>>>(apB, apA, cxP, cyP, pA, rB, x, setA);

    // steady its 1..19; write-triples alternate {rA,pB,apA} / {rB,pA,apB}
    float* TA[3] = {rA, pB, apA};
    float* TB[3] = {rB, pA, apB};
    const float *ri = pA, *pi = pA, *ai = rB;   // r0==p0
    const double *dIn = setA; double *dOut = setB;
    const double *rnIn = rnA; double *rnOut = rnB;
    for (int it = 1; it < CG_ITERS; ++it) {
        float** T = (it & 1) ? TA : TB;
        k_iter<<<NBLK, blk, 0, stream>>>(cxP, cyP, ri, T[0], pi, T[1], ai, T[2],
                                         x, dIn, dOut, rnIn, rnOut, it == 1 ? 1 : 0);
        ri = T[0]; pi = T[1]; ai = T[2];
        { const double* s = dIn; dIn = dOut; dOut = (double*)s; }
        { const double* s = rnIn; rnIn = rnOut; rnOut = (double*)s; }
    }

    k_fin<<<NBLK, blk, 0, stream>>>(u, pi, x, dIn, rnIn);
}